// Round 3
// baseline (636.908 us; speedup 1.0000x reference)
//
#include <hip/hip_runtime.h>
#include <stdint.h>
#include <math.h>

// ---------------------------------------------------------------------------
// HybridNN: MLP (split-bf16 MFMA GEMMs) + 12-qubit statevector circuit with
// lazy (GF2-linear) CNOT tracking and 4-gate-fused rotation passes.
// ---------------------------------------------------------------------------

typedef __attribute__((ext_vector_type(4))) float f32x4;
typedef __attribute__((ext_vector_type(8))) short bf16x8;
typedef __attribute__((ext_vector_type(8))) unsigned short u16x8;

struct QArgs {
  uint16_t xc[12][16];    // per fused pass: XOR combos of the 4 gate masks
  uint8_t  np[12][8];     // per fused pass: 8 non-pivot bit positions (coset reps)
  uint16_t grow[12][4];   // per pass, per gate: role row (A^-1 row)
  uint16_t frqi_mask;     // final col_0(A)
  uint16_t frqi_rows[12]; // final rows of A^-1 (w=0..11)
};
static_assert(sizeof(QArgs) <= 1024, "kernarg too big");

__device__ __forceinline__ int swz(int j) { return j ^ (j >> 5) ^ (j >> 10); }

__device__ __forceinline__ unsigned short f2bf(float x) {
  unsigned u = __float_as_uint(x);
  unsigned r = (u + 0x7fffu + ((u >> 16) & 1u)) >> 16;  // RNE
  return (unsigned short)r;
}
__device__ __forceinline__ float bf2f(unsigned short h) {
  return __uint_as_float(((unsigned)h) << 16);
}

// ---------------- conv_x: x (4096x2048 f32) -> A3 = [hi|hi|lo] bf16 (4096x6144)
__global__ __launch_bounds__(256) void conv_x_kernel(const float* __restrict__ x,
                                                     unsigned short* __restrict__ A3) {
  int g = blockIdx.x * 256 + threadIdx.x;   // 1,048,576 threads
  int m = g >> 8;
  int c8 = (g & 255) << 3;
  const float4* src = (const float4*)(x + (size_t)m * 2048 + c8);
  float4 v0 = src[0], v1 = src[1];
  float vs[8] = {v0.x, v0.y, v0.z, v0.w, v1.x, v1.y, v1.z, v1.w};
  u16x8 h8, l8;
#pragma unroll
  for (int i = 0; i < 8; ++i) {
    unsigned short h = f2bf(vs[i]);
    h8[i] = h;
    l8[i] = f2bf(vs[i] - bf2f(h));
  }
  size_t base = (size_t)m * 6144 + c8;
  *(u16x8*)(A3 + base)        = h8;
  *(u16x8*)(A3 + base + 2048) = h8;
  *(u16x8*)(A3 + base + 4096) = l8;
}

// ------------- conv_w: W (KxN f32, row-major) -> BT = N x 3K bf16, segs [hi|lo|hi]
__global__ __launch_bounds__(256) void conv_w_kernel(const float* __restrict__ W,
                                                     unsigned short* __restrict__ BT,
                                                     int K, int N) {
  __shared__ float tile[64][65];
  int k0 = blockIdx.x * 64, n0 = blockIdx.y * 64;
  int t = threadIdx.x;
  int li = t >> 2;             // 0..63
  int lj = (t & 3) << 4;       // 0,16,32,48
  const float* src = W + (size_t)(k0 + li) * N + n0 + lj;
#pragma unroll
  for (int c = 0; c < 16; c += 4) {
    float4 v = *(const float4*)(src + c);
    tile[li][lj + c + 0] = v.x; tile[li][lj + c + 1] = v.y;
    tile[li][lj + c + 2] = v.z; tile[li][lj + c + 3] = v.w;
  }
  __syncthreads();
  int n = n0 + li;
  int kk = lj;
  u16x8 hi2[2], lo2[2];
#pragma unroll
  for (int c = 0; c < 16; ++c) {
    float v = tile[kk + c][li];
    unsigned short h = f2bf(v);
    hi2[c >> 3][c & 7] = h;
    lo2[c >> 3][c & 7] = f2bf(v - bf2f(h));
  }
  size_t rb = (size_t)n * (3 * (size_t)K) + k0 + kk;
  *(u16x8*)(BT + rb)         = hi2[0];
  *(u16x8*)(BT + rb + 8)     = hi2[1];
  *(u16x8*)(BT + rb + K)     = lo2[0];
  *(u16x8*)(BT + rb + K + 8) = lo2[1];
  *(u16x8*)(BT + rb + 2*K)     = hi2[0];
  *(u16x8*)(BT + rb + 2*K + 8) = hi2[1];
}

// ---------------- MFMA GEMM: C = A(MxK) * B^T(NxK) + bias; EPI=1: relu+write H3
// EPI=2: write f32 C.
template <int BM, int EPI>
__global__ __launch_bounds__(256) void gemm_kernel(
    const unsigned short* __restrict__ A, const unsigned short* __restrict__ B,
    const float* __restrict__ bias, float* __restrict__ Cf,
    unsigned short* __restrict__ Hb, int M, int N, int K) {
  constexpr int BK = 64;
  constexpr int MI = BM / 32;        // M frags per wave
  constexpr int AQ = BM / 32;        // A stage chunks per thread
  __shared__ unsigned short smA[BM * BK];
  __shared__ unsigned short smB[64 * BK];
  const int t = threadIdx.x, wave = t >> 6, lane = t & 63;
  const int m0 = blockIdx.x * BM, n0 = blockIdx.y * 64;
  const int wr = wave >> 1, wc = wave & 1;

  f32x4 acc[MI][2];
#pragma unroll
  for (int i = 0; i < MI; ++i)
#pragma unroll
    for (int j = 0; j < 2; ++j) acc[i][j] = (f32x4)0.0f;

  // staging geometry (linear tile coords; dst XOR-swizzled)
  int arow[AQ], acol[AQ], adst[AQ];
#pragma unroll
  for (int q = 0; q < AQ; ++q) {
    int off = (q * 256 + t) * 16;
    arow[q] = off >> 7; acol[q] = off & 127;
    adst[q] = off ^ ((arow[q] & 7) << 4);
  }
  int brow[2], bcol[2], bdst[2];
#pragma unroll
  for (int q = 0; q < 2; ++q) {
    int off = (q * 256 + t) * 16;
    brow[q] = off >> 7; bcol[q] = off & 127;
    bdst[q] = off ^ ((brow[q] & 7) << 4);
  }

  for (int kt = 0; kt < K; kt += BK) {
    uint4 ra[AQ], rb[2];
#pragma unroll
    for (int q = 0; q < AQ; ++q)
      ra[q] = *(const uint4*)((const char*)A + ((size_t)(m0 + arow[q]) * K + kt) * 2 + acol[q]);
#pragma unroll
    for (int q = 0; q < 2; ++q)
      rb[q] = *(const uint4*)((const char*)B + ((size_t)(n0 + brow[q]) * K + kt) * 2 + bcol[q]);
    __syncthreads();           // previous tile's readers done
#pragma unroll
    for (int q = 0; q < AQ; ++q) *(uint4*)((char*)smA + adst[q]) = ra[q];
#pragma unroll
    for (int q = 0; q < 2; ++q)  *(uint4*)((char*)smB + bdst[q]) = rb[q];
    __syncthreads();           // tile visible

#pragma unroll
    for (int kk = 0; kk < 2; ++kk) {
      const int kbyte = kk * 64 + (lane >> 4) * 16;
      bf16x8 af[MI], bfr[2];
#pragma unroll
      for (int mi = 0; mi < MI; ++mi) {
        int row = wr * (BM / 2) + mi * 16 + (lane & 15);
        int off = (row * 128 + kbyte) ^ ((row & 7) << 4);
        af[mi] = *(const bf16x8*)((const char*)smA + off);
      }
#pragma unroll
      for (int ni = 0; ni < 2; ++ni) {
        int row = wc * 32 + ni * 16 + (lane & 15);
        int off = (row * 128 + kbyte) ^ ((row & 7) << 4);
        bfr[ni] = *(const bf16x8*)((const char*)smB + off);
      }
#pragma unroll
      for (int mi = 0; mi < MI; ++mi)
#pragma unroll
        for (int ni = 0; ni < 2; ++ni)
          acc[mi][ni] = __builtin_amdgcn_mfma_f32_16x16x32_bf16(af[mi], bfr[ni], acc[mi][ni], 0, 0, 0);
    }
    // NOTE: no barrier here — next iteration's pre-write barrier separates
    // this iteration's LDS readers from the next tile's LDS writers.
  }

  const int r0 = (lane >> 4) * 4;
  const int cn = lane & 15;
#pragma unroll
  for (int mi = 0; mi < MI; ++mi) {
#pragma unroll
    for (int ni = 0; ni < 2; ++ni) {
      int n = n0 + wc * 32 + ni * 16 + cn;
      float bn = bias[n];
#pragma unroll
      for (int r = 0; r < 4; ++r) {
        int m = m0 + wr * (BM / 2) + mi * 16 + r0 + r;
        float v = acc[mi][ni][r] + bn;
        if constexpr (EPI == 1) {
          v = fmaxf(v, 0.0f);
          unsigned short h = f2bf(v);
          unsigned short l = f2bf(v - bf2f(h));
          size_t rbase = (size_t)m * (3 * (size_t)N);
          Hb[rbase + n] = h;
          Hb[rbase + N + n] = h;
          Hb[rbase + 2 * N + n] = l;
        } else {
          Cf[(size_t)m * N + n] = v;
        }
      }
    }
  }
}

// ---------------- quantum kernel: one block per batch item -------------------
__global__ __launch_bounds__(256) void quantum_kernel(
    const float* __restrict__ x, const float* __restrict__ com,
    const float* __restrict__ asz, float* __restrict__ out, QArgs qa) {
  __shared__ float2 st[4096];
  __shared__ float gm[48 * 8];
  __shared__ float xrow[2048];
  __shared__ float red[4];
  const int t = threadIdx.x;
  const int b = blockIdx.x;

  // stage x row (img angles), compute gate matrices, zero state
  {
    const float4* xs = (const float4*)(x + (size_t)b * 2048);
    ((float4*)xrow)[t] = xs[t];
    ((float4*)xrow)[t + 256] = xs[t + 256];
  }
  if (t < 48) {
    float phi = asz[t * 3 + 0], th = asz[t * 3 + 1], om = asz[t * 3 + 2];
    float sth, cth, sa, ca, sb, cb;
    sincosf(0.5f * th, &sth, &cth);
    sincosf(0.5f * (phi + om), &sa, &ca);
    sincosf(0.5f * (phi - om), &sb, &cb);
    float* g = gm + t * 8;
    g[0] =  ca * cth; g[1] = -sa * cth;   // m00 = e^{-i(phi+om)/2} cos(th/2)
    g[2] = -cb * sth; g[3] = -sb * sth;   // m01 = -e^{+i(phi-om)/2} sin(th/2)
    g[4] =  cb * sth; g[5] = -sb * sth;   // m10 = e^{-i(phi-om)/2} sin(th/2)
    g[6] =  ca * cth; g[7] =  sa * cth;   // m11 = e^{+i(phi+om)/2} cos(th/2)
  }
#pragma unroll
  for (int s = 0; s < 16; ++s) st[s * 256 + t] = make_float2(0.f, 0.f);
  __syncthreads();

  // init: H^{1..7} + FRQI(com,7): 256 real amps
  {
    int jj = t & 127, b0 = t >> 7;
    int p = __brev((unsigned)jj) >> 25;  // 7-bit reverse
    float ang = 0.5f * com[(size_t)b * 128 + p];
    float s, c;
    sincosf(ang, &s, &c);
    float val = (b0 ? s : c) * 0.08838834764831845f;  // 2^-3.5
    int j = (b0 << 11) | (jj << 4);
    st[swz(j)] = make_float2(val, 0.f);
  }
  __syncthreads();

  // 12 fused passes (4 Rot gates each), CNOTs folded into masks/roles
#pragma unroll 1
  for (int p = 0; p < 12; ++p) {
    int rep = 0;
#pragma unroll
    for (int i = 0; i < 8; ++i) rep |= ((t >> i) & 1) << qa.np[p][i];
    int adr[16];
    float2 v[16];
#pragma unroll
    for (int s = 0; s < 16; ++s) {
      adr[s] = swz(rep ^ (int)qa.xc[p][s]);
      v[s] = st[adr[s]];
    }
    const int l = p / 3, gbase = (p % 3) * 4;
#pragma unroll
    for (int k = 0; k < 4; ++k) {
      const float* g = gm + (l * 12 + gbase + k) * 8;
      int rho = __popc(rep & (int)qa.grow[p][k]) & 1;
      float caa_r = rho ? g[6] : g[0], caa_i = rho ? g[7] : g[1];
      float cab_r = rho ? g[4] : g[2], cab_i = rho ? g[5] : g[3];
      float cba_r = rho ? g[2] : g[4], cba_i = rho ? g[3] : g[5];
      float cbb_r = rho ? g[0] : g[6], cbb_i = rho ? g[1] : g[7];
      const int bk = 1 << k;
#pragma unroll
      for (int s = 0; s < 16; ++s) {
        if (s & bk) continue;
        float2 a = v[s], bb = v[s | bk];
        float nar = caa_r * a.x - caa_i * a.y + cab_r * bb.x - cab_i * bb.y;
        float nai = caa_r * a.y + caa_i * a.x + cab_r * bb.y + cab_i * bb.x;
        float nbr = cba_r * a.x - cba_i * a.y + cbb_r * bb.x - cbb_i * bb.y;
        float nbi = cba_r * a.y + cba_i * a.x + cbb_r * bb.y + cbb_i * bb.x;
        v[s] = make_float2(nar, nai);
        v[s | bk] = make_float2(nbr, nbi);
      }
    }
#pragma unroll
    for (int s = 0; s < 16; ++s) st[adr[s]] = v[s];
    __syncthreads();
  }

  // final FRQI(img,11): controlled-RY on wire 0, lazy masks
  {
    const int mF = qa.frqi_mask;
    const int hb = 31 - __clz(mF);
    const int lowmask = (1 << hb) - 1;
    const int r0m = qa.frqi_rows[0];
#pragma unroll 1
    for (int q = 0; q < 8; ++q) {
      int u = q * 256 + t;
      int jA = ((u & ~lowmask) << 1) | (u & lowmask);
      int jB = jA ^ mF;
      int pidx = 0;
#pragma unroll
      for (int w = 1; w < 12; ++w)
        pidx |= (__popc(jA & (int)qa.frqi_rows[w]) & 1) << (w - 1);
      float hal = -0.5f * xrow[pidx];
      float s, c;
      sincosf(hal, &s, &c);
      int sA = swz(jA), sB = swz(jB);
      float2 a = st[sA], bb = st[sB];
      int rho = __popc(jA & r0m) & 1;
      float2 v0 = rho ? bb : a;
      float2 v1 = rho ? a : bb;
      float2 o0 = make_float2(c * v0.x - s * v1.x, c * v0.y - s * v1.y);
      float2 o1 = make_float2(s * v0.x + c * v1.x, s * v0.y + c * v1.y);
      if (rho) { st[sB] = o0; st[sA] = o1; } else { st[sA] = o0; st[sB] = o1; }
    }
  }
  __syncthreads();

  // readout: P(wire0=1) - P(wire0=0)
  {
    const int r0m = qa.frqi_rows[0];
    float sum = 0.f;
#pragma unroll
    for (int s = 0; s < 16; ++s) {
      int j = t * 16 + s;
      float2 a = st[swz(j)];
      float mag = a.x * a.x + a.y * a.y;
      sum += (__popc(j & r0m) & 1) ? mag : -mag;
    }
#pragma unroll
    for (int o = 32; o > 0; o >>= 1) sum += __shfl_down(sum, o, 64);
    if ((t & 63) == 0) red[t >> 6] = sum;
    __syncthreads();
    if (t == 0) out[b] = red[0] + red[1] + red[2] + red[3];
  }
}

// ---------------------------------------------------------------------------
extern "C" void kernel_launch(void* const* d_in, const int* in_sizes, int n_in,
                              void* d_out, int out_size, void* d_ws, size_t ws_size,
                              hipStream_t stream) {
  (void)in_sizes; (void)n_in; (void)out_size; (void)ws_size;
  const float* x   = (const float*)d_in[0];
  const float* W1  = (const float*)d_in[1];
  const float* b1  = (const float*)d_in[2];
  const float* W2  = (const float*)d_in[3];
  const float* b2  = (const float*)d_in[4];
  const float* asz = (const float*)d_in[5];
  float* out = (float*)d_out;

  char* ws = (char*)d_ws;
  unsigned short* A3  = (unsigned short*)ws; ws += (size_t)4096 * 6144 * 2;
  unsigned short* B3T = (unsigned short*)ws; ws += (size_t)512 * 6144 * 2;
  unsigned short* H3  = (unsigned short*)ws; ws += (size_t)4096 * 1536 * 2;
  unsigned short* W23 = (unsigned short*)ws; ws += (size_t)128 * 1536 * 2;
  float* com = (float*)ws;                   ws += (size_t)4096 * 128 * 4;

  // ----- host: lazy CNOT tracking (circuit is input-independent) -----
  QArgs qa;
  int cols[12], rows[12];
  for (int w = 0; w < 12; ++w) cols[w] = rows[w] = 1 << (11 - w);
  for (int l = 0; l < 4; ++l) {
    for (int g = 0; g < 3; ++g) {
      int p = l * 3 + g;
      int m[4];
      for (int k = 0; k < 4; ++k) {
        int w = g * 4 + k;
        m[k] = cols[w];
        qa.grow[p][k] = (uint16_t)rows[w];
      }
      for (int s = 0; s < 16; ++s) {
        int v = 0;
        for (int k = 0; k < 4; ++k)
          if (s & (1 << k)) v ^= m[k];
        qa.xc[p][s] = (uint16_t)v;
      }
      int mm[4] = {m[0], m[1], m[2], m[3]};
      int piv = 0;
      for (int k = 0; k < 4; ++k) {
        int pb = 31 - __builtin_clz((unsigned)mm[k]);
        piv |= 1 << pb;
        for (int k2 = k + 1; k2 < 4; ++k2)
          if (mm[k2] & (1 << pb)) mm[k2] ^= mm[k];
      }
      int c = 0;
      for (int bit = 0; bit < 12; ++bit)
        if (!(piv & (1 << bit))) qa.np[p][c++] = (uint8_t)bit;
    }
    int r = l % 11 + 1;
    for (int w = 0; w < 12; ++w) {
      int cw = w, tw = (w + r) % 12;
      cols[cw] ^= cols[tw];   // A <- A o L (CNOT ctrl=w, tgt=(w+r)%12)
      rows[tw] ^= rows[cw];   // A^-1 <- L o A^-1
    }
  }
  qa.frqi_mask = (uint16_t)cols[0];
  for (int w = 0; w < 12; ++w) qa.frqi_rows[w] = (uint16_t)rows[w];

  // ----- pipeline -----
  conv_x_kernel<<<4096, 256, 0, stream>>>(x, A3);
  conv_w_kernel<<<dim3(32, 8), 256, 0, stream>>>(W1, B3T, 2048, 512);
  conv_w_kernel<<<dim3(8, 2), 256, 0, stream>>>(W2, W23, 512, 128);
  gemm_kernel<128, 1><<<dim3(32, 8), 256, 0, stream>>>(A3, B3T, b1, nullptr, H3, 4096, 512, 6144);
  gemm_kernel<64, 2><<<dim3(64, 2), 256, 0, stream>>>(H3, W23, b2, com, nullptr, 4096, 128, 1536);
  quantum_kernel<<<4096, 256, 0, stream>>>(x, com, asz, out, qa);
}

// Round 4
// 566.069 us; speedup vs baseline: 1.1251x; 1.1251x over previous
//
#include <hip/hip_runtime.h>
#include <stdint.h>
#include <math.h>

// ---------------------------------------------------------------------------
// HybridNN: MLP (split-bf16 MFMA GEMMs) + 12-qubit statevector circuit with
// lazy (GF2-linear) CNOT tracking and 4-gate-fused rotation passes.
// R4: sign-trick coefficients, pre-swizzled XOR tables, fused FRQI+readout,
// fast sincos, LDS 40960B -> 4 blocks/CU.
// ---------------------------------------------------------------------------

typedef __attribute__((ext_vector_type(4))) float f32x4;
typedef __attribute__((ext_vector_type(8))) short bf16x8;
typedef __attribute__((ext_vector_type(8))) unsigned short u16x8;

struct QArgs {
  uint16_t xcs[12][16];  // swz(xc)<<3 : byte-addr XOR combos of 4 gate masks
  uint16_t anp[12][8];   // swz(1<<np[i])<<3 : per-t-bit addr contribution
  uint8_t  gm8[12][4];   // rho over t bits: rho_k = popc(t & gm8)&1
  uint32_t cmb_t[8];     // final pass: (pidx<<16)|(rho<<15)|(swz(jA)<<3), t-bit i
  uint32_t cmb_q[8];     // same, q-bit contribution
  uint32_t smF8;         // swz(mF)<<3
};
static_assert(sizeof(QArgs) <= 1024, "kernarg too big");

__device__ __host__ __forceinline__ int swz(int j) { return j ^ (j >> 5) ^ (j >> 10); }

__device__ __forceinline__ unsigned short f2bf(float x) {
  unsigned u = __float_as_uint(x);
  unsigned r = (u + 0x7fffu + ((u >> 16) & 1u)) >> 16;  // RNE
  return (unsigned short)r;
}
__device__ __forceinline__ float bf2f(unsigned short h) {
  return __uint_as_float(((unsigned)h) << 16);
}
__device__ __forceinline__ float xsign(float v, unsigned sgn) {
  return __uint_as_float(__float_as_uint(v) ^ sgn);
}

// ---------------- conv_x: x (4096x2048 f32) -> A3 = [hi|hi|lo] bf16 (4096x6144)
__global__ __launch_bounds__(256) void conv_x_kernel(const float* __restrict__ x,
                                                     unsigned short* __restrict__ A3) {
  int g = blockIdx.x * 256 + threadIdx.x;   // 1,048,576 threads
  int m = g >> 8;
  int c8 = (g & 255) << 3;
  const float4* src = (const float4*)(x + (size_t)m * 2048 + c8);
  float4 v0 = src[0], v1 = src[1];
  float vs[8] = {v0.x, v0.y, v0.z, v0.w, v1.x, v1.y, v1.z, v1.w};
  u16x8 h8, l8;
#pragma unroll
  for (int i = 0; i < 8; ++i) {
    unsigned short h = f2bf(vs[i]);
    h8[i] = h;
    l8[i] = f2bf(vs[i] - bf2f(h));
  }
  size_t base = (size_t)m * 6144 + c8;
  *(u16x8*)(A3 + base)        = h8;
  *(u16x8*)(A3 + base + 2048) = h8;
  *(u16x8*)(A3 + base + 4096) = l8;
}

// ------------- conv_w: W (KxN f32, row-major) -> BT = N x 3K bf16, segs [hi|lo|hi]
__global__ __launch_bounds__(256) void conv_w_kernel(const float* __restrict__ W,
                                                     unsigned short* __restrict__ BT,
                                                     int K, int N) {
  __shared__ float tile[64][65];
  int k0 = blockIdx.x * 64, n0 = blockIdx.y * 64;
  int t = threadIdx.x;
  int li = t >> 2;             // 0..63
  int lj = (t & 3) << 4;       // 0,16,32,48
  const float* src = W + (size_t)(k0 + li) * N + n0 + lj;
#pragma unroll
  for (int c = 0; c < 16; c += 4) {
    float4 v = *(const float4*)(src + c);
    tile[li][lj + c + 0] = v.x; tile[li][lj + c + 1] = v.y;
    tile[li][lj + c + 2] = v.z; tile[li][lj + c + 3] = v.w;
  }
  __syncthreads();
  int n = n0 + li;
  int kk = lj;
  u16x8 hi2[2], lo2[2];
#pragma unroll
  for (int c = 0; c < 16; ++c) {
    float v = tile[kk + c][li];
    unsigned short h = f2bf(v);
    hi2[c >> 3][c & 7] = h;
    lo2[c >> 3][c & 7] = f2bf(v - bf2f(h));
  }
  size_t rb = (size_t)n * (3 * (size_t)K) + k0 + kk;
  *(u16x8*)(BT + rb)         = hi2[0];
  *(u16x8*)(BT + rb + 8)     = hi2[1];
  *(u16x8*)(BT + rb + K)     = lo2[0];
  *(u16x8*)(BT + rb + K + 8) = lo2[1];
  *(u16x8*)(BT + rb + 2*K)     = hi2[0];
  *(u16x8*)(BT + rb + 2*K + 8) = hi2[1];
}

// ---------------- MFMA GEMM: C = A(MxK) * B^T(NxK) + bias; EPI=1: relu+write H3
// EPI=2: write f32 C.
template <int BM, int EPI>
__global__ __launch_bounds__(256) void gemm_kernel(
    const unsigned short* __restrict__ A, const unsigned short* __restrict__ B,
    const float* __restrict__ bias, float* __restrict__ Cf,
    unsigned short* __restrict__ Hb, int M, int N, int K) {
  constexpr int BK = 64;
  constexpr int MI = BM / 32;        // M frags per wave
  constexpr int AQ = BM / 32;        // A stage chunks per thread
  __shared__ unsigned short smA[BM * BK];
  __shared__ unsigned short smB[64 * BK];
  const int t = threadIdx.x, wave = t >> 6, lane = t & 63;
  const int m0 = blockIdx.x * BM, n0 = blockIdx.y * 64;
  const int wr = wave >> 1, wc = wave & 1;

  f32x4 acc[MI][2];
#pragma unroll
  for (int i = 0; i < MI; ++i)
#pragma unroll
    for (int j = 0; j < 2; ++j) acc[i][j] = (f32x4)0.0f;

  // staging geometry (linear tile coords; dst XOR-swizzled)
  int arow[AQ], acol[AQ], adst[AQ];
#pragma unroll
  for (int q = 0; q < AQ; ++q) {
    int off = (q * 256 + t) * 16;
    arow[q] = off >> 7; acol[q] = off & 127;
    adst[q] = off ^ ((arow[q] & 7) << 4);
  }
  int brow[2], bcol[2], bdst[2];
#pragma unroll
  for (int q = 0; q < 2; ++q) {
    int off = (q * 256 + t) * 16;
    brow[q] = off >> 7; bcol[q] = off & 127;
    bdst[q] = off ^ ((brow[q] & 7) << 4);
  }

  for (int kt = 0; kt < K; kt += BK) {
    uint4 ra[AQ], rb[2];
#pragma unroll
    for (int q = 0; q < AQ; ++q)
      ra[q] = *(const uint4*)((const char*)A + ((size_t)(m0 + arow[q]) * K + kt) * 2 + acol[q]);
#pragma unroll
    for (int q = 0; q < 2; ++q)
      rb[q] = *(const uint4*)((const char*)B + ((size_t)(n0 + brow[q]) * K + kt) * 2 + bcol[q]);
    __syncthreads();           // previous tile's readers done
#pragma unroll
    for (int q = 0; q < AQ; ++q) *(uint4*)((char*)smA + adst[q]) = ra[q];
#pragma unroll
    for (int q = 0; q < 2; ++q)  *(uint4*)((char*)smB + bdst[q]) = rb[q];
    __syncthreads();           // tile visible

#pragma unroll
    for (int kk = 0; kk < 2; ++kk) {
      const int kbyte = kk * 64 + (lane >> 4) * 16;
      bf16x8 af[MI], bfr[2];
#pragma unroll
      for (int mi = 0; mi < MI; ++mi) {
        int row = wr * (BM / 2) + mi * 16 + (lane & 15);
        int off = (row * 128 + kbyte) ^ ((row & 7) << 4);
        af[mi] = *(const bf16x8*)((const char*)smA + off);
      }
#pragma unroll
      for (int ni = 0; ni < 2; ++ni) {
        int row = wc * 32 + ni * 16 + (lane & 15);
        int off = (row * 128 + kbyte) ^ ((row & 7) << 4);
        bfr[ni] = *(const bf16x8*)((const char*)smB + off);
      }
#pragma unroll
      for (int mi = 0; mi < MI; ++mi)
#pragma unroll
        for (int ni = 0; ni < 2; ++ni)
          acc[mi][ni] = __builtin_amdgcn_mfma_f32_16x16x32_bf16(af[mi], bfr[ni], acc[mi][ni], 0, 0, 0);
    }
    // no barrier: next iteration's pre-write barrier separates readers/writers
  }

  const int r0 = (lane >> 4) * 4;
  const int cn = lane & 15;
#pragma unroll
  for (int mi = 0; mi < MI; ++mi) {
#pragma unroll
    for (int ni = 0; ni < 2; ++ni) {
      int n = n0 + wc * 32 + ni * 16 + cn;
      float bn = bias[n];
#pragma unroll
      for (int r = 0; r < 4; ++r) {
        int m = m0 + wr * (BM / 2) + mi * 16 + r0 + r;
        float v = acc[mi][ni][r] + bn;
        if constexpr (EPI == 1) {
          v = fmaxf(v, 0.0f);
          unsigned short h = f2bf(v);
          unsigned short l = f2bf(v - bf2f(h));
          size_t rbase = (size_t)m * (3 * (size_t)N);
          Hb[rbase + n] = h;
          Hb[rbase + N + n] = h;
          Hb[rbase + 2 * N + n] = l;
        } else {
          Cf[(size_t)m * N + n] = v;
        }
      }
    }
  }
}

// ---------------- prep_gates: 48 gate matrices -> (g0,g1,g2,g3) table ---------
__global__ __launch_bounds__(64) void prep_gates(const float* __restrict__ asz,
                                                 float* __restrict__ gcoef) {
  int t = threadIdx.x;
  if (t < 48) {
    float phi = asz[t * 3 + 0], th = asz[t * 3 + 1], om = asz[t * 3 + 2];
    float sth, cth, sa, ca, sb, cb;
    sincosf(0.5f * th, &sth, &cth);
    sincosf(0.5f * (phi + om), &sa, &ca);
    sincosf(0.5f * (phi - om), &sb, &cb);
    float4 g;
    g.x =  ca * cth;   // g0 : Re m00 (= Re m11)
    g.y = -sa * cth;   // g1 : Im m00 (= -Im m11)
    g.z = -cb * sth;   // g2 : Re m01 (= -Re m10)
    g.w = -sb * sth;   // g3 : Im m01 (= Im m10)
    ((float4*)gcoef)[t] = g;
  }
}

// ---------------- quantum kernel: one block per batch item -------------------
__global__ __launch_bounds__(256) void quantum_kernel(
    const float* __restrict__ x, const float* __restrict__ com,
    const float* __restrict__ gcoef, float* __restrict__ out, QArgs qa) {
  __shared__ float2 st[4096];     // 32768 B
  __shared__ float xrow[2048];    //  8192 B  (total 40960 -> 4 blocks/CU)
  const int t = threadIdx.x;
  const int b = blockIdx.x;
  const float4* __restrict__ gc4 = (const float4*)gcoef;

  // stage x row (img angles); zero state
  {
    const float4* xs = (const float4*)(x + (size_t)b * 2048);
    ((float4*)xrow)[t] = xs[t];
    ((float4*)xrow)[t + 256] = xs[t + 256];
  }
#pragma unroll
  for (int s = 0; s < 16; ++s) st[s * 256 + t] = make_float2(0.f, 0.f);
  __syncthreads();

  // init: H^{1..7} + FRQI(com,7): 256 real amps
  {
    int jj = t & 127, b0 = t >> 7;
    int p = __brev((unsigned)jj) >> 25;  // 7-bit reverse
    float ang = 0.5f * com[(size_t)b * 128 + p];
    float s = __sinf(ang), c = __cosf(ang);
    float val = (b0 ? s : c) * 0.08838834764831845f;  // 2^-3.5
    int j = (b0 << 11) | (jj << 4);
    *(float2*)((char*)st + (swz(j) << 3)) = make_float2(val, 0.f);
  }
  __syncthreads();

  // 12 fused passes (4 Rot gates each), CNOTs folded into masks/roles
#pragma unroll 1
  for (int p = 0; p < 12; ++p) {
    // byte-swizzled coset base: srB = swz(rep)<<3, built per t-bit
    int srB = 0;
#pragma unroll
    for (int i = 0; i < 8; ++i) srB ^= ((t >> i) & 1) ? (int)qa.anp[p][i] : 0;

    // gate coefficients (wave-uniform loads) + per-thread role signs
    const int gi = (p / 3) * 12 + (p % 3) * 4;
    float4 gk0 = gc4[gi + 0], gk1 = gc4[gi + 1], gk2 = gc4[gi + 2], gk3 = gc4[gi + 3];
    unsigned sg0 = (unsigned)__popc(t & (int)qa.gm8[p][0]) << 31;
    unsigned sg1 = (unsigned)__popc(t & (int)qa.gm8[p][1]) << 31;
    unsigned sg2 = (unsigned)__popc(t & (int)qa.gm8[p][2]) << 31;
    unsigned sg3 = (unsigned)__popc(t & (int)qa.gm8[p][3]) << 31;

    int aB[16];
    float2 v[16];
#pragma unroll
    for (int s = 0; s < 16; ++s) {
      aB[s] = srB ^ (int)qa.xcs[p][s];
      v[s] = *(const float2*)((const char*)st + aB[s]);
    }

#pragma unroll
    for (int k = 0; k < 4; ++k) {
      float4 g = (k == 0) ? gk0 : (k == 1) ? gk1 : (k == 2) ? gk2 : gk3;
      unsigned sg = (k == 0) ? sg0 : (k == 1) ? sg1 : (k == 2) ? sg2 : sg3;
      const float G0 = g.x, G3 = g.w;
      const float S1 = xsign(g.y, sg), S2 = xsign(g.z, sg);
      const int bk = 1 << k;
#pragma unroll
      for (int s = 0; s < 16; ++s) {
        if (s & bk) continue;
        float2 a = v[s], bb = v[s | bk];
        float nar = G0 * a.x - S1 * a.y + S2 * bb.x - G3 * bb.y;
        float nai = G0 * a.y + S1 * a.x + S2 * bb.y + G3 * bb.x;
        float nbr = -S2 * a.x - G3 * a.y + G0 * bb.x + S1 * bb.y;
        float nbi = -S2 * a.y + G3 * a.x + G0 * bb.y - S1 * bb.x;
        v[s] = make_float2(nar, nai);
        v[s | bk] = make_float2(nbr, nbi);
      }
    }
#pragma unroll
    for (int s = 0; s < 16; ++s) *(float2*)((char*)st + aB[s]) = v[s];
    __syncthreads();
  }

  // fused final FRQI(img,11) + readout:
  // per pair: |o1|^2-|o0|^2 = -(-1)^rho cos(x) (|a|^2-|b|^2) - 2 sin(x) <a,b>
  float accv = 0.f;
  {
    unsigned C0 = 0;
#pragma unroll
    for (int i = 0; i < 8; ++i) C0 ^= ((t >> i) & 1) ? qa.cmb_t[i] : 0u;
#pragma unroll
    for (int q = 0; q < 8; ++q) {
      unsigned C = C0 ^ qa.cmb_q[q];
      int aA = (int)(C & 0x7FF8u);
      int aB2 = aA ^ (int)qa.smF8;
      float ang = xrow[C >> 16];
      float sx = __sinf(ang), cx = __cosf(ang);
      float2 a = *(const float2*)((const char*)st + aA);
      float2 bb = *(const float2*)((const char*)st + aB2);
      float da = a.x * a.x + a.y * a.y;
      float db = bb.x * bb.x + bb.y * bb.y;
      float d = da - db;
      float dot = a.x * bb.x + a.y * bb.y;
      unsigned sgn = (C & 0x8000u) << 16;
      float dp = xsign(d, sgn);
      accv -= cx * dp + 2.0f * sx * dot;
    }
  }
  __syncthreads();   // all reads of st/xrow done before scratch reuse

  // reduce: wave shfl + cross-wave via xrow scratch
#pragma unroll
  for (int o = 32; o > 0; o >>= 1) accv += __shfl_down(accv, o, 64);
  if ((t & 63) == 0) xrow[t >> 6] = accv;
  __syncthreads();
  if (t == 0) out[b] = xrow[0] + xrow[1] + xrow[2] + xrow[3];
}

// ---------------------------------------------------------------------------
static inline int par16(int v) { return __builtin_popcount((unsigned)v) & 1; }

extern "C" void kernel_launch(void* const* d_in, const int* in_sizes, int n_in,
                              void* d_out, int out_size, void* d_ws, size_t ws_size,
                              hipStream_t stream) {
  (void)in_sizes; (void)n_in; (void)out_size; (void)ws_size;
  const float* x   = (const float*)d_in[0];
  const float* W1  = (const float*)d_in[1];
  const float* b1  = (const float*)d_in[2];
  const float* W2  = (const float*)d_in[3];
  const float* b2  = (const float*)d_in[4];
  const float* asz = (const float*)d_in[5];
  float* out = (float*)d_out;

  char* ws = (char*)d_ws;
  unsigned short* A3  = (unsigned short*)ws; ws += (size_t)4096 * 6144 * 2;
  unsigned short* B3T = (unsigned short*)ws; ws += (size_t)512 * 6144 * 2;
  unsigned short* H3  = (unsigned short*)ws; ws += (size_t)4096 * 1536 * 2;
  unsigned short* W23 = (unsigned short*)ws; ws += (size_t)128 * 1536 * 2;
  float* com = (float*)ws;                   ws += (size_t)4096 * 128 * 4;
  float* gcoef = (float*)ws;                 ws += (size_t)48 * 4 * 4;

  // ----- host: lazy CNOT tracking (circuit is input-independent) -----
  QArgs qa;
  int cols[12], rows[12];
  for (int w = 0; w < 12; ++w) cols[w] = rows[w] = 1 << (11 - w);
  int hswz;
  for (int l = 0; l < 4; ++l) {
    for (int g = 0; g < 3; ++g) {
      int p = l * 3 + g;
      int m[4], grow[4];
      for (int k = 0; k < 4; ++k) {
        int w = g * 4 + k;
        m[k] = cols[w];
        grow[k] = rows[w];
      }
      for (int s = 0; s < 16; ++s) {
        int v = 0;
        for (int k = 0; k < 4; ++k)
          if (s & (1 << k)) v ^= m[k];
        hswz = v ^ (v >> 5) ^ (v >> 10);
        qa.xcs[p][s] = (uint16_t)(hswz << 3);
      }
      int mm[4] = {m[0], m[1], m[2], m[3]};
      int piv = 0;
      for (int k = 0; k < 4; ++k) {
        int pb = 31 - __builtin_clz((unsigned)mm[k]);
        piv |= 1 << pb;
        for (int k2 = k + 1; k2 < 4; ++k2)
          if (mm[k2] & (1 << pb)) mm[k2] ^= mm[k];
      }
      int npb[8], c = 0;
      for (int bit = 0; bit < 12; ++bit)
        if (!(piv & (1 << bit))) npb[c++] = bit;
      for (int i = 0; i < 8; ++i) {
        int bv = 1 << npb[i];
        hswz = bv ^ (bv >> 5) ^ (bv >> 10);
        qa.anp[p][i] = (uint16_t)(hswz << 3);
      }
      for (int k = 0; k < 4; ++k) {
        int mask8 = 0;
        for (int i = 0; i < 8; ++i)
          mask8 |= ((grow[k] >> npb[i]) & 1) << i;
        qa.gm8[p][k] = (uint8_t)mask8;
      }
    }
    int r = l % 11 + 1;
    for (int w = 0; w < 12; ++w) {
      int cw = w, tw = (w + r) % 12;
      cols[cw] ^= cols[tw];   // A <- A o L (CNOT ctrl=w, tgt=(w+r)%12)
      rows[tw] ^= rows[cw];   // A^-1 <- L o A^-1
    }
  }
  // final FRQI fold: combined constants, all GF2-linear in u = (q<<8)|t
  {
    int mF = cols[0];
    int hb = 31 - __builtin_clz((unsigned)mF);
    int lowmask = (1 << hb) - 1;
    auto jAof = [&](int u) { return ((u & ~lowmask) << 1) | (u & lowmask); };
    auto cmbof = [&](int j) -> uint32_t {
      int pidx = 0;
      for (int w = 1; w < 12; ++w)
        pidx |= par16(j & rows[w]) << (w - 1);
      int rho = par16(j & rows[0]);
      int sj = j ^ (j >> 5) ^ (j >> 10);
      return ((uint32_t)pidx << 16) | ((uint32_t)rho << 15) | (uint32_t)(sj << 3);
    };
    for (int i = 0; i < 8; ++i) qa.cmb_t[i] = cmbof(jAof(1 << i));
    for (int q = 0; q < 8; ++q) qa.cmb_q[q] = cmbof(jAof(q << 8));
    int sF = mF ^ (mF >> 5) ^ (mF >> 10);
    qa.smF8 = (uint32_t)(sF << 3);
  }

  // ----- pipeline -----
  conv_x_kernel<<<4096, 256, 0, stream>>>(x, A3);
  conv_w_kernel<<<dim3(32, 8), 256, 0, stream>>>(W1, B3T, 2048, 512);
  conv_w_kernel<<<dim3(8, 2), 256, 0, stream>>>(W2, W23, 512, 128);
  prep_gates<<<1, 64, 0, stream>>>(asz, gcoef);
  gemm_kernel<128, 1><<<dim3(32, 8), 256, 0, stream>>>(A3, B3T, b1, nullptr, H3, 4096, 512, 6144);
  gemm_kernel<64, 2><<<dim3(64, 2), 256, 0, stream>>>(H3, W23, b2, com, nullptr, 4096, 128, 1536);
  quantum_kernel<<<4096, 256, 0, stream>>>(x, com, gcoef, out, qa);
}

// Round 8
// 473.498 us; speedup vs baseline: 1.3451x; 1.1955x over previous
//
#include <hip/hip_runtime.h>
#include <stdint.h>
#include <math.h>

// ---------------------------------------------------------------------------
// HybridNN: MLP (split-bf16 MFMA GEMMs) + 12-qubit statevector circuit with
// lazy (GF2-linear) CNOT tracking and 4-gate-fused rotation passes.
// R5..R8: complex butterflies via v_pk_fma_f32 (2xFP32/instr, op_sel swap +
// neg modifiers) -> 8 instrs/butterfly instead of 16.
// ---------------------------------------------------------------------------

typedef __attribute__((ext_vector_type(4))) float f32x4;
typedef __attribute__((ext_vector_type(2))) float f32x2;
typedef __attribute__((ext_vector_type(8))) short bf16x8;
typedef __attribute__((ext_vector_type(8))) unsigned short u16x8;

struct QArgs {
  uint16_t xcs[12][16];  // swz(xc)<<3 : byte-addr XOR combos of 4 gate masks
  uint16_t anp[12][8];   // swz(1<<np[i])<<3 : per-t-bit addr contribution
  uint8_t  gm8[12][4];   // rho over t bits: rho_k = popc(t & gm8)&1
  uint32_t cmb_t[8];     // final pass: (pidx<<16)|(rho<<15)|(swz(jA)<<3), t-bit i
  uint32_t cmb_q[8];     // same, q-bit contribution
  uint32_t smF8;         // swz(mF)<<3
};
static_assert(sizeof(QArgs) <= 1024, "kernarg too big");

__device__ __host__ __forceinline__ int swz(int j) { return j ^ (j >> 5) ^ (j >> 10); }

__device__ __forceinline__ unsigned short f2bf(float x) {
  unsigned u = __float_as_uint(x);
  unsigned r = (u + 0x7fffu + ((u >> 16) & 1u)) >> 16;  // RNE
  return (unsigned short)r;
}
__device__ __forceinline__ float bf2f(unsigned short h) {
  return __uint_as_float(((unsigned)h) << 16);
}
__device__ __forceinline__ float xsign(float v, unsigned sgn) {
  return __uint_as_float(__float_as_uint(v) ^ sgn);
}

// ---- packed dual-FP32 helpers (VOP3P). coef in src0, value in src1. ----
__device__ __forceinline__ f32x2 pkmul(f32x2 a, f32x2 b) {
  f32x2 d;
  asm("v_pk_mul_f32 %0, %1, %2" : "=v"(d) : "v"(a), "v"(b));
  return d;
}
__device__ __forceinline__ f32x2 pkfma(f32x2 a, f32x2 b, f32x2 c) {
  f32x2 d = c;
  asm("v_pk_fma_f32 %0, %1, %2, %0" : "+v"(d) : "v"(a), "v"(b));
  return d;
}
// value swapped (hi->lo, lo->hi), low product negated: (-a*b.hi, +a*b.lo)
__device__ __forceinline__ f32x2 pkfma_swapneglo(f32x2 a, f32x2 b, f32x2 c) {
  f32x2 d = c;
  asm("v_pk_fma_f32 %0, %1, %2, %0 op_sel:[0,1,0] op_sel_hi:[1,0,1] neg_lo:[0,1,0]"
      : "+v"(d) : "v"(a), "v"(b));
  return d;
}
// value swapped, high product negated: (+a*b.hi, -a*b.lo)
__device__ __forceinline__ f32x2 pkfma_swapneghi(f32x2 a, f32x2 b, f32x2 c) {
  f32x2 d = c;
  asm("v_pk_fma_f32 %0, %1, %2, %0 op_sel:[0,1,0] op_sel_hi:[1,0,1] neg_hi:[0,1,0]"
      : "+v"(d) : "v"(a), "v"(b));
  return d;
}
// both products negated: (-a*b.lo, -a*b.hi)
__device__ __forceinline__ f32x2 pkfma_negboth(f32x2 a, f32x2 b, f32x2 c) {
  f32x2 d = c;
  asm("v_pk_fma_f32 %0, %1, %2, %0 neg_lo:[0,1,0] neg_hi:[0,1,0]"
      : "+v"(d) : "v"(a), "v"(b));
  return d;
}

// complex 2x2 rotation butterfly on packed (re,im) amps A,B:
//  na = (G0*Ax - S1*Ay + S2*Bx - G3*By , G0*Ay + S1*Ax + S2*By + G3*Bx)
//  nb = (-S2*Ax - G3*Ay + G0*Bx + S1*By, -S2*Ay + G3*Ax + G0*By - S1*Bx)
__device__ __forceinline__ void bfly(f32x2& A, f32x2& B,
                                     f32x2 G0, f32x2 S1, f32x2 S2, f32x2 G3) {
  f32x2 na = pkmul(G0, A);
  na = pkfma_swapneglo(S1, A, na);
  na = pkfma(S2, B, na);
  na = pkfma_swapneglo(G3, B, na);
  f32x2 nb = pkmul(G0, B);
  nb = pkfma_swapneghi(S1, B, nb);
  nb = pkfma_negboth(S2, A, nb);
  nb = pkfma_swapneglo(G3, A, nb);
  A = na;
  B = nb;
}

// ---------------- conv_x: x (4096x2048 f32) -> A3 = [hi|hi|lo] bf16 (4096x6144)
__global__ __launch_bounds__(256) void conv_x_kernel(const float* __restrict__ x,
                                                     unsigned short* __restrict__ A3) {
  int g = blockIdx.x * 256 + threadIdx.x;   // 1,048,576 threads
  int m = g >> 8;
  int c8 = (g & 255) << 3;
  const float4* src = (const float4*)(x + (size_t)m * 2048 + c8);
  float4 v0 = src[0], v1 = src[1];
  float vs[8] = {v0.x, v0.y, v0.z, v0.w, v1.x, v1.y, v1.z, v1.w};
  u16x8 h8, l8;
#pragma unroll
  for (int i = 0; i < 8; ++i) {
    unsigned short h = f2bf(vs[i]);
    h8[i] = h;
    l8[i] = f2bf(vs[i] - bf2f(h));
  }
  size_t base = (size_t)m * 6144 + c8;
  *(u16x8*)(A3 + base)        = h8;
  *(u16x8*)(A3 + base + 2048) = h8;
  *(u16x8*)(A3 + base + 4096) = l8;
}

// ------------- conv_w: W (KxN f32, row-major) -> BT = N x 3K bf16, segs [hi|lo|hi]
__global__ __launch_bounds__(256) void conv_w_kernel(const float* __restrict__ W,
                                                     unsigned short* __restrict__ BT,
                                                     int K, int N) {
  __shared__ float tile[64][65];
  int k0 = blockIdx.x * 64, n0 = blockIdx.y * 64;
  int t = threadIdx.x;
  int li = t >> 2;             // 0..63
  int lj = (t & 3) << 4;       // 0,16,32,48
  const float* src = W + (size_t)(k0 + li) * N + n0 + lj;
#pragma unroll
  for (int c = 0; c < 16; c += 4) {
    float4 v = *(const float4*)(src + c);
    tile[li][lj + c + 0] = v.x; tile[li][lj + c + 1] = v.y;
    tile[li][lj + c + 2] = v.z; tile[li][lj + c + 3] = v.w;
  }
  __syncthreads();
  int n = n0 + li;
  int kk = lj;
  u16x8 hi2[2], lo2[2];
#pragma unroll
  for (int c = 0; c < 16; ++c) {
    float v = tile[kk + c][li];
    unsigned short h = f2bf(v);
    hi2[c >> 3][c & 7] = h;
    lo2[c >> 3][c & 7] = f2bf(v - bf2f(h));
  }
  size_t rb = (size_t)n * (3 * (size_t)K) + k0 + kk;
  *(u16x8*)(BT + rb)         = hi2[0];
  *(u16x8*)(BT + rb + 8)     = hi2[1];
  *(u16x8*)(BT + rb + K)     = lo2[0];
  *(u16x8*)(BT + rb + K + 8) = lo2[1];
  *(u16x8*)(BT + rb + 2*K)     = hi2[0];
  *(u16x8*)(BT + rb + 2*K + 8) = hi2[1];
}

// ---------------- MFMA GEMM: C = A(MxK) * B^T(NxK) + bias; EPI=1: relu+write H3
// EPI=2: write f32 C.
template <int BM, int EPI>
__global__ __launch_bounds__(256) void gemm_kernel(
    const unsigned short* __restrict__ A, const unsigned short* __restrict__ B,
    const float* __restrict__ bias, float* __restrict__ Cf,
    unsigned short* __restrict__ Hb, int M, int N, int K) {
  constexpr int BK = 64;
  constexpr int MI = BM / 32;        // M frags per wave
  constexpr int AQ = BM / 32;        // A stage chunks per thread
  __shared__ unsigned short smA[BM * BK];
  __shared__ unsigned short smB[64 * BK];
  const int t = threadIdx.x, wave = t >> 6, lane = t & 63;
  const int m0 = blockIdx.x * BM, n0 = blockIdx.y * 64;
  const int wr = wave >> 1, wc = wave & 1;

  f32x4 acc[MI][2];
#pragma unroll
  for (int i = 0; i < MI; ++i)
#pragma unroll
    for (int j = 0; j < 2; ++j) acc[i][j] = (f32x4)0.0f;

  // staging geometry (linear tile coords; dst XOR-swizzled)
  int arow[AQ], acol[AQ], adst[AQ];
#pragma unroll
  for (int q = 0; q < AQ; ++q) {
    int off = (q * 256 + t) * 16;
    arow[q] = off >> 7; acol[q] = off & 127;
    adst[q] = off ^ ((arow[q] & 7) << 4);
  }
  int brow[2], bcol[2], bdst[2];
#pragma unroll
  for (int q = 0; q < 2; ++q) {
    int off = (q * 256 + t) * 16;
    brow[q] = off >> 7; bcol[q] = off & 127;
    bdst[q] = off ^ ((brow[q] & 7) << 4);
  }

  for (int kt = 0; kt < K; kt += BK) {
    uint4 ra[AQ], rb[2];
#pragma unroll
    for (int q = 0; q < AQ; ++q)
      ra[q] = *(const uint4*)((const char*)A + ((size_t)(m0 + arow[q]) * K + kt) * 2 + acol[q]);
#pragma unroll
    for (int q = 0; q < 2; ++q)
      rb[q] = *(const uint4*)((const char*)B + ((size_t)(n0 + brow[q]) * K + kt) * 2 + bcol[q]);
    __syncthreads();           // previous tile's readers done
#pragma unroll
    for (int q = 0; q < AQ; ++q) *(uint4*)((char*)smA + adst[q]) = ra[q];
#pragma unroll
    for (int q = 0; q < 2; ++q)  *(uint4*)((char*)smB + bdst[q]) = rb[q];
    __syncthreads();           // tile visible

#pragma unroll
    for (int kk = 0; kk < 2; ++kk) {
      const int kbyte = kk * 64 + (lane >> 4) * 16;
      bf16x8 af[MI], bfr[2];
#pragma unroll
      for (int mi = 0; mi < MI; ++mi) {
        int row = wr * (BM / 2) + mi * 16 + (lane & 15);
        int off = (row * 128 + kbyte) ^ ((row & 7) << 4);
        af[mi] = *(const bf16x8*)((const char*)smA + off);
      }
#pragma unroll
      for (int ni = 0; ni < 2; ++ni) {
        int row = wc * 32 + ni * 16 + (lane & 15);
        int off = (row * 128 + kbyte) ^ ((row & 7) << 4);
        bfr[ni] = *(const bf16x8*)((const char*)smB + off);
      }
#pragma unroll
      for (int mi = 0; mi < MI; ++mi)
#pragma unroll
        for (int ni = 0; ni < 2; ++ni)
          acc[mi][ni] = __builtin_amdgcn_mfma_f32_16x16x32_bf16(af[mi], bfr[ni], acc[mi][ni], 0, 0, 0);
    }
    // no barrier: next iteration's pre-write barrier separates readers/writers
  }

  const int r0 = (lane >> 4) * 4;
  const int cn = lane & 15;
#pragma unroll
  for (int mi = 0; mi < MI; ++mi) {
#pragma unroll
    for (int ni = 0; ni < 2; ++ni) {
      int n = n0 + wc * 32 + ni * 16 + cn;
      float bn = bias[n];
#pragma unroll
      for (int r = 0; r < 4; ++r) {
        int m = m0 + wr * (BM / 2) + mi * 16 + r0 + r;
        float v = acc[mi][ni][r] + bn;
        if constexpr (EPI == 1) {
          v = fmaxf(v, 0.0f);
          unsigned short h = f2bf(v);
          unsigned short l = f2bf(v - bf2f(h));
          size_t rbase = (size_t)m * (3 * (size_t)N);
          Hb[rbase + n] = h;
          Hb[rbase + N + n] = h;
          Hb[rbase + 2 * N + n] = l;
        } else {
          Cf[(size_t)m * N + n] = v;
        }
      }
    }
  }
}

// ---------------- prep_gates: 48 gate matrices -> (g0,g1,g2,g3) table ---------
__global__ __launch_bounds__(64) void prep_gates(const float* __restrict__ asz,
                                                 float* __restrict__ gcoef) {
  int t = threadIdx.x;
  if (t < 48) {
    float phi = asz[t * 3 + 0], th = asz[t * 3 + 1], om = asz[t * 3 + 2];
    float sth, cth, sa, ca, sb, cb;
    sincosf(0.5f * th, &sth, &cth);
    sincosf(0.5f * (phi + om), &sa, &ca);
    sincosf(0.5f * (phi - om), &sb, &cb);
    float4 g;
    g.x =  ca * cth;   // g0 : Re m00 (= Re m11)
    g.y = -sa * cth;   // g1 : Im m00 (= -Im m11)
    g.z = -cb * sth;   // g2 : Re m01 (= -Re m10)
    g.w = -sb * sth;   // g3 : Im m01 (= Im m10)
    ((float4*)gcoef)[t] = g;
  }
}

// ---------------- quantum kernel: one block per batch item -------------------
__global__ __launch_bounds__(256) void quantum_kernel(
    const float* __restrict__ x, const float* __restrict__ com,
    const float* __restrict__ gcoef, float* __restrict__ out, QArgs qa) {
  __shared__ f32x2 st[4096];      // 32768 B
  __shared__ float xrow[2048];    //  8192 B  (total 40960 -> 4 blocks/CU)
  const int t = threadIdx.x;
  const int b = blockIdx.x;
  const float4* __restrict__ gc4 = (const float4*)gcoef;

  // stage x row (img angles); zero state
  {
    const float4* xs = (const float4*)(x + (size_t)b * 2048);
    ((float4*)xrow)[t] = xs[t];
    ((float4*)xrow)[t + 256] = xs[t + 256];
  }
#pragma unroll
  for (int s = 0; s < 16; ++s) st[s * 256 + t] = (f32x2){0.f, 0.f};
  __syncthreads();

  // init: H^{1..7} + FRQI(com,7): 256 real amps
  {
    int jj = t & 127, b0 = t >> 7;
    int p = __brev((unsigned)jj) >> 25;  // 7-bit reverse
    float ang = 0.5f * com[(size_t)b * 128 + p];
    float s = __sinf(ang), c = __cosf(ang);
    float val = (b0 ? s : c) * 0.08838834764831845f;  // 2^-3.5
    int j = (b0 << 11) | (jj << 4);
    *(f32x2*)((char*)st + (swz(j) << 3)) = (f32x2){val, 0.f};
  }
  __syncthreads();

  // 12 fused passes (4 Rot gates each), CNOTs folded into masks/roles
#pragma unroll 1
  for (int p = 0; p < 12; ++p) {
    // byte-swizzled coset base: srB = swz(rep)<<3, built per t-bit
    int srB = 0;
#pragma unroll
    for (int i = 0; i < 8; ++i) srB ^= ((t >> i) & 1) ? (int)qa.anp[p][i] : 0;

    // gate coefficients (wave-uniform loads) + per-thread role signs
    const int gi = (p / 3) * 12 + (p % 3) * 4;
    float4 gk0 = gc4[gi + 0], gk1 = gc4[gi + 1], gk2 = gc4[gi + 2], gk3 = gc4[gi + 3];
    unsigned sg0 = (unsigned)__popc(t & (int)qa.gm8[p][0]) << 31;
    unsigned sg1 = (unsigned)__popc(t & (int)qa.gm8[p][1]) << 31;
    unsigned sg2 = (unsigned)__popc(t & (int)qa.gm8[p][2]) << 31;
    unsigned sg3 = (unsigned)__popc(t & (int)qa.gm8[p][3]) << 31;

    int aB[16];
    f32x2 v[16];
#pragma unroll
    for (int s = 0; s < 16; ++s) {
      aB[s] = srB ^ (int)qa.xcs[p][s];
      v[s] = *(const f32x2*)((const char*)st + aB[s]);
    }

#pragma unroll
    for (int k = 0; k < 4; ++k) {
      float4 g = (k == 0) ? gk0 : (k == 1) ? gk1 : (k == 2) ? gk2 : gk3;
      unsigned sg = (k == 0) ? sg0 : (k == 1) ? sg1 : (k == 2) ? sg2 : sg3;
      f32x2 G0 = (f32x2)(g.x);
      f32x2 S1 = (f32x2)(xsign(g.y, sg));
      f32x2 S2 = (f32x2)(xsign(g.z, sg));
      f32x2 G3 = (f32x2)(g.w);
      const int bk = 1 << k;
#pragma unroll
      for (int s = 0; s < 16; ++s) {
        if (s & bk) continue;
        bfly(v[s], v[s | bk], G0, S1, S2, G3);
      }
    }
#pragma unroll
    for (int s = 0; s < 16; ++s) *(f32x2*)((char*)st + aB[s]) = v[s];
    __syncthreads();
  }

  // fused final FRQI(img,11) + readout:
  // per pair: |o1|^2-|o0|^2 = -(-1)^rho cos(x) (|a|^2-|b|^2) - 2 sin(x) <a,b>
  float accv = 0.f;
  {
    unsigned C0 = 0;
#pragma unroll
    for (int i = 0; i < 8; ++i) C0 ^= ((t >> i) & 1) ? qa.cmb_t[i] : 0u;
#pragma unroll
    for (int q = 0; q < 8; ++q) {
      unsigned C = C0 ^ qa.cmb_q[q];
      int aA = (int)(C & 0x7FF8u);
      int aB2 = aA ^ (int)qa.smF8;
      float ang = xrow[C >> 16];
      float sx = __sinf(ang), cx = __cosf(ang);
      f32x2 a = *(const f32x2*)((const char*)st + aA);
      f32x2 bb = *(const f32x2*)((const char*)st + aB2);
      float da = a.x * a.x + a.y * a.y;
      float db = bb.x * bb.x + bb.y * bb.y;
      float d = da - db;
      float dot = a.x * bb.x + a.y * bb.y;
      unsigned sgn = (C & 0x8000u) << 16;
      float dp = xsign(d, sgn);
      accv -= cx * dp + 2.0f * sx * dot;
    }
  }
  __syncthreads();   // all reads of st/xrow done before scratch reuse

  // reduce: wave shfl + cross-wave via xrow scratch
#pragma unroll
  for (int o = 32; o > 0; o >>= 1) accv += __shfl_down(accv, o, 64);
  if ((t & 63) == 0) xrow[t >> 6] = accv;
  __syncthreads();
  if (t == 0) out[b] = xrow[0] + xrow[1] + xrow[2] + xrow[3];
}

// ---------------------------------------------------------------------------
static inline int par16(int v) { return __builtin_popcount((unsigned)v) & 1; }

extern "C" void kernel_launch(void* const* d_in, const int* in_sizes, int n_in,
                              void* d_out, int out_size, void* d_ws, size_t ws_size,
                              hipStream_t stream) {
  (void)in_sizes; (void)n_in; (void)out_size; (void)ws_size;
  const float* x   = (const float*)d_in[0];
  const float* W1  = (const float*)d_in[1];
  const float* b1  = (const float*)d_in[2];
  const float* W2  = (const float*)d_in[3];
  const float* b2  = (const float*)d_in[4];
  const float* asz = (const float*)d_in[5];
  float* out = (float*)d_out;

  char* ws = (char*)d_ws;
  unsigned short* A3  = (unsigned short*)ws; ws += (size_t)4096 * 6144 * 2;
  unsigned short* B3T = (unsigned short*)ws; ws += (size_t)512 * 6144 * 2;
  unsigned short* H3  = (unsigned short*)ws; ws += (size_t)4096 * 1536 * 2;
  unsigned short* W23 = (unsigned short*)ws; ws += (size_t)128 * 1536 * 2;
  float* com = (float*)ws;                   ws += (size_t)4096 * 128 * 4;
  float* gcoef = (float*)ws;                 ws += (size_t)48 * 4 * 4;

  // ----- host: lazy CNOT tracking (circuit is input-independent) -----
  QArgs qa;
  int cols[12], rows[12];
  for (int w = 0; w < 12; ++w) cols[w] = rows[w] = 1 << (11 - w);
  int hswz;
  for (int l = 0; l < 4; ++l) {
    for (int g = 0; g < 3; ++g) {
      int p = l * 3 + g;
      int m[4], grow[4];
      for (int k = 0; k < 4; ++k) {
        int w = g * 4 + k;
        m[k] = cols[w];
        grow[k] = rows[w];
      }
      for (int s = 0; s < 16; ++s) {
        int v = 0;
        for (int k = 0; k < 4; ++k)
          if (s & (1 << k)) v ^= m[k];
        hswz = v ^ (v >> 5) ^ (v >> 10);
        qa.xcs[p][s] = (uint16_t)(hswz << 3);
      }
      int mm[4] = {m[0], m[1], m[2], m[3]};
      int piv = 0;
      for (int k = 0; k < 4; ++k) {
        int pb = 31 - __builtin_clz((unsigned)mm[k]);
        piv |= 1 << pb;
        for (int k2 = k + 1; k2 < 4; ++k2)
          if (mm[k2] & (1 << pb)) mm[k2] ^= mm[k];
      }
      int npb[8], c = 0;
      for (int bit = 0; bit < 12; ++bit)
        if (!(piv & (1 << bit))) npb[c++] = bit;
      for (int i = 0; i < 8; ++i) {
        int bv = 1 << npb[i];
        hswz = bv ^ (bv >> 5) ^ (bv >> 10);
        qa.anp[p][i] = (uint16_t)(hswz << 3);
      }
      for (int k = 0; k < 4; ++k) {
        int mask8 = 0;
        for (int i = 0; i < 8; ++i)
          mask8 |= ((grow[k] >> npb[i]) & 1) << i;
        qa.gm8[p][k] = (uint8_t)mask8;
      }
    }
    int r = l % 11 + 1;
    for (int w = 0; w < 12; ++w) {
      int cw = w, tw = (w + r) % 12;
      cols[cw] ^= cols[tw];   // A <- A o L (CNOT ctrl=w, tgt=(w+r)%12)
      rows[tw] ^= rows[cw];   // A^-1 <- L o A^-1
    }
  }
  // final FRQI fold: combined constants, all GF2-linear in u = (q<<8)|t
  {
    int mF = cols[0];
    int hb = 31 - __builtin_clz((unsigned)mF);
    int lowmask = (1 << hb) - 1;
    auto jAof = [&](int u) { return ((u & ~lowmask) << 1) | (u & lowmask); };
    auto cmbof = [&](int j) -> uint32_t {
      int pidx = 0;
      for (int w = 1; w < 12; ++w)
        pidx |= par16(j & rows[w]) << (w - 1);
      int rho = par16(j & rows[0]);
      int sj = j ^ (j >> 5) ^ (j >> 10);
      return ((uint32_t)pidx << 16) | ((uint32_t)rho << 15) | (uint32_t)(sj << 3);
    };
    for (int i = 0; i < 8; ++i) qa.cmb_t[i] = cmbof(jAof(1 << i));
    for (int q = 0; q < 8; ++q) qa.cmb_q[q] = cmbof(jAof(q << 8));
    int sF = mF ^ (mF >> 5) ^ (mF >> 10);
    qa.smF8 = (uint32_t)(sF << 3);
  }

  // ----- pipeline -----
  conv_x_kernel<<<4096, 256, 0, stream>>>(x, A3);
  conv_w_kernel<<<dim3(32, 8), 256, 0, stream>>>(W1, B3T, 2048, 512);
  conv_w_kernel<<<dim3(8, 2), 256, 0, stream>>>(W2, W23, 512, 128);
  prep_gates<<<1, 64, 0, stream>>>(asz, gcoef);
  gemm_kernel<128, 1><<<dim3(32, 8), 256, 0, stream>>>(A3, B3T, b1, nullptr, H3, 4096, 512, 6144);
  gemm_kernel<64, 2><<<dim3(64, 2), 256, 0, stream>>>(H3, W23, b2, com, nullptr, 4096, 128, 1536);
  quantum_kernel<<<4096, 256, 0, stream>>>(x, com, gcoef, out, qa);
}

// Round 9
// 464.770 us; speedup vs baseline: 1.3704x; 1.0188x over previous
//
#include <hip/hip_runtime.h>
#include <stdint.h>
#include <math.h>

// ---------------------------------------------------------------------------
// HybridNN: MLP (split-bf16 MFMA GEMMs) + 12-qubit statevector circuit with
// lazy (GF2-linear) CNOT tracking and 4-gate-fused rotation passes.
// R9: GEMM K-split across blockIdx.z (occupancy 11%->~45%) + depth-1 global
// prefetch; epilogue moved to reduce kernels (deterministic, no atomics).
// ---------------------------------------------------------------------------

typedef __attribute__((ext_vector_type(4))) float f32x4;
typedef __attribute__((ext_vector_type(2))) float f32x2;
typedef __attribute__((ext_vector_type(8))) short bf16x8;
typedef __attribute__((ext_vector_type(8))) unsigned short u16x8;
typedef __attribute__((ext_vector_type(4))) unsigned short u16x4;

struct QArgs {
  uint16_t xcs[12][16];  // swz(xc)<<3 : byte-addr XOR combos of 4 gate masks
  uint16_t anp[12][8];   // swz(1<<np[i])<<3 : per-t-bit addr contribution
  uint8_t  gm8[12][4];   // rho over t bits: rho_k = popc(t & gm8)&1
  uint32_t cmb_t[8];     // final pass: (pidx<<16)|(rho<<15)|(swz(jA)<<3), t-bit i
  uint32_t cmb_q[8];     // same, q-bit contribution
  uint32_t smF8;         // swz(mF)<<3
};
static_assert(sizeof(QArgs) <= 1024, "kernarg too big");

__device__ __host__ __forceinline__ int swz(int j) { return j ^ (j >> 5) ^ (j >> 10); }

__device__ __forceinline__ unsigned short f2bf(float x) {
  unsigned u = __float_as_uint(x);
  unsigned r = (u + 0x7fffu + ((u >> 16) & 1u)) >> 16;  // RNE
  return (unsigned short)r;
}
__device__ __forceinline__ float bf2f(unsigned short h) {
  return __uint_as_float(((unsigned)h) << 16);
}
__device__ __forceinline__ float xsign(float v, unsigned sgn) {
  return __uint_as_float(__float_as_uint(v) ^ sgn);
}

// ---- packed dual-FP32 helpers (VOP3P). coef in src0, value in src1. ----
__device__ __forceinline__ f32x2 pkmul(f32x2 a, f32x2 b) {
  f32x2 d;
  asm("v_pk_mul_f32 %0, %1, %2" : "=v"(d) : "v"(a), "v"(b));
  return d;
}
__device__ __forceinline__ f32x2 pkfma(f32x2 a, f32x2 b, f32x2 c) {
  f32x2 d = c;
  asm("v_pk_fma_f32 %0, %1, %2, %0" : "+v"(d) : "v"(a), "v"(b));
  return d;
}
// value swapped (hi->lo, lo->hi), low product negated: (-a*b.hi, +a*b.lo)
__device__ __forceinline__ f32x2 pkfma_swapneglo(f32x2 a, f32x2 b, f32x2 c) {
  f32x2 d = c;
  asm("v_pk_fma_f32 %0, %1, %2, %0 op_sel:[0,1,0] op_sel_hi:[1,0,1] neg_lo:[0,1,0]"
      : "+v"(d) : "v"(a), "v"(b));
  return d;
}
// value swapped, high product negated: (+a*b.hi, -a*b.lo)
__device__ __forceinline__ f32x2 pkfma_swapneghi(f32x2 a, f32x2 b, f32x2 c) {
  f32x2 d = c;
  asm("v_pk_fma_f32 %0, %1, %2, %0 op_sel:[0,1,0] op_sel_hi:[1,0,1] neg_hi:[0,1,0]"
      : "+v"(d) : "v"(a), "v"(b));
  return d;
}
// both products negated: (-a*b.lo, -a*b.hi)
__device__ __forceinline__ f32x2 pkfma_negboth(f32x2 a, f32x2 b, f32x2 c) {
  f32x2 d = c;
  asm("v_pk_fma_f32 %0, %1, %2, %0 neg_lo:[0,1,0] neg_hi:[0,1,0]"
      : "+v"(d) : "v"(a), "v"(b));
  return d;
}

// complex 2x2 rotation butterfly on packed (re,im) amps A,B
__device__ __forceinline__ void bfly(f32x2& A, f32x2& B,
                                     f32x2 G0, f32x2 S1, f32x2 S2, f32x2 G3) {
  f32x2 na = pkmul(G0, A);
  na = pkfma_swapneglo(S1, A, na);
  na = pkfma(S2, B, na);
  na = pkfma_swapneglo(G3, B, na);
  f32x2 nb = pkmul(G0, B);
  nb = pkfma_swapneghi(S1, B, nb);
  nb = pkfma_negboth(S2, A, nb);
  nb = pkfma_swapneglo(G3, A, nb);
  A = na;
  B = nb;
}

// ---------------- conv_x: x (4096x2048 f32) -> A3 = [hi|hi|lo] bf16 (4096x6144)
__global__ __launch_bounds__(256) void conv_x_kernel(const float* __restrict__ x,
                                                     unsigned short* __restrict__ A3) {
  int g = blockIdx.x * 256 + threadIdx.x;   // 1,048,576 threads
  int m = g >> 8;
  int c8 = (g & 255) << 3;
  const float4* src = (const float4*)(x + (size_t)m * 2048 + c8);
  float4 v0 = src[0], v1 = src[1];
  float vs[8] = {v0.x, v0.y, v0.z, v0.w, v1.x, v1.y, v1.z, v1.w};
  u16x8 h8, l8;
#pragma unroll
  for (int i = 0; i < 8; ++i) {
    unsigned short h = f2bf(vs[i]);
    h8[i] = h;
    l8[i] = f2bf(vs[i] - bf2f(h));
  }
  size_t base = (size_t)m * 6144 + c8;
  *(u16x8*)(A3 + base)        = h8;
  *(u16x8*)(A3 + base + 2048) = h8;
  *(u16x8*)(A3 + base + 4096) = l8;
}

// ------------- conv_w: W (KxN f32, row-major) -> BT = N x 3K bf16, segs [hi|lo|hi]
__global__ __launch_bounds__(256) void conv_w_kernel(const float* __restrict__ W,
                                                     unsigned short* __restrict__ BT,
                                                     int K, int N) {
  __shared__ float tile[64][65];
  int k0 = blockIdx.x * 64, n0 = blockIdx.y * 64;
  int t = threadIdx.x;
  int li = t >> 2;             // 0..63
  int lj = (t & 3) << 4;       // 0,16,32,48
  const float* src = W + (size_t)(k0 + li) * N + n0 + lj;
#pragma unroll
  for (int c = 0; c < 16; c += 4) {
    float4 v = *(const float4*)(src + c);
    tile[li][lj + c + 0] = v.x; tile[li][lj + c + 1] = v.y;
    tile[li][lj + c + 2] = v.z; tile[li][lj + c + 3] = v.w;
  }
  __syncthreads();
  int n = n0 + li;
  int kk = lj;
  u16x8 hi2[2], lo2[2];
#pragma unroll
  for (int c = 0; c < 16; ++c) {
    float v = tile[kk + c][li];
    unsigned short h = f2bf(v);
    hi2[c >> 3][c & 7] = h;
    lo2[c >> 3][c & 7] = f2bf(v - bf2f(h));
  }
  size_t rb = (size_t)n * (3 * (size_t)K) + k0 + kk;
  *(u16x8*)(BT + rb)         = hi2[0];
  *(u16x8*)(BT + rb + 8)     = hi2[1];
  *(u16x8*)(BT + rb + K)     = lo2[0];
  *(u16x8*)(BT + rb + K + 8) = lo2[1];
  *(u16x8*)(BT + rb + 2*K)     = hi2[0];
  *(u16x8*)(BT + rb + 2*K + 8) = hi2[1];
}

// ---------------- MFMA GEMM partial: P[z] = A(MxK-slice) * B^T(NxK-slice)
// K-split over blockIdx.z (KS columns each); depth-1 global prefetch.
template <int BM>
__global__ __launch_bounds__(256) void gemm_part(
    const unsigned short* __restrict__ A, const unsigned short* __restrict__ B,
    float* __restrict__ P, int M, int N, int K, int KS) {
  constexpr int BK = 64;
  constexpr int MI = BM / 32;        // M frags per wave
  constexpr int AQ = BM / 32;        // A stage chunks per thread
  __shared__ unsigned short smA[BM * BK];
  __shared__ unsigned short smB[64 * BK];
  const int t = threadIdx.x, wave = t >> 6, lane = t & 63;
  const int m0 = blockIdx.x * BM, n0 = blockIdx.y * 64;
  const int k0 = blockIdx.z * KS, k1 = k0 + KS;
  const int wr = wave >> 1, wc = wave & 1;

  f32x4 acc[MI][2];
#pragma unroll
  for (int i = 0; i < MI; ++i)
#pragma unroll
    for (int j = 0; j < 2; ++j) acc[i][j] = (f32x4)0.0f;

  // staging geometry (linear tile coords; dst XOR-swizzled)
  int arow[AQ], acol[AQ], adst[AQ];
#pragma unroll
  for (int q = 0; q < AQ; ++q) {
    int off = (q * 256 + t) * 16;
    arow[q] = off >> 7; acol[q] = off & 127;
    adst[q] = off ^ ((arow[q] & 7) << 4);
  }
  int brow[2], bcol[2], bdst[2];
#pragma unroll
  for (int q = 0; q < 2; ++q) {
    int off = (q * 256 + t) * 16;
    brow[q] = off >> 7; bcol[q] = off & 127;
    bdst[q] = off ^ ((brow[q] & 7) << 4);
  }

  uint4 ra[AQ], rb[2];
  auto LOADK = [&](int kt) {
#pragma unroll
    for (int q = 0; q < AQ; ++q)
      ra[q] = *(const uint4*)((const char*)A + ((size_t)(m0 + arow[q]) * K + kt) * 2 + acol[q]);
#pragma unroll
    for (int q = 0; q < 2; ++q)
      rb[q] = *(const uint4*)((const char*)B + ((size_t)(n0 + brow[q]) * K + kt) * 2 + bcol[q]);
  };

  LOADK(k0);
  for (int kt = k0; kt < k1; kt += BK) {
    __syncthreads();           // previous tile's readers done
#pragma unroll
    for (int q = 0; q < AQ; ++q) *(uint4*)((char*)smA + adst[q]) = ra[q];
#pragma unroll
    for (int q = 0; q < 2; ++q)  *(uint4*)((char*)smB + bdst[q]) = rb[q];
    __syncthreads();           // tile visible
    if (kt + BK < k1) LOADK(kt + BK);   // prefetch in flight across MFMA phase

#pragma unroll
    for (int kk = 0; kk < 2; ++kk) {
      const int kbyte = kk * 64 + (lane >> 4) * 16;
      bf16x8 af[MI], bfr[2];
#pragma unroll
      for (int mi = 0; mi < MI; ++mi) {
        int row = wr * (BM / 2) + mi * 16 + (lane & 15);
        int off = (row * 128 + kbyte) ^ ((row & 7) << 4);
        af[mi] = *(const bf16x8*)((const char*)smA + off);
      }
#pragma unroll
      for (int ni = 0; ni < 2; ++ni) {
        int row = wc * 32 + ni * 16 + (lane & 15);
        int off = (row * 128 + kbyte) ^ ((row & 7) << 4);
        bfr[ni] = *(const bf16x8*)((const char*)smB + off);
      }
#pragma unroll
      for (int mi = 0; mi < MI; ++mi)
#pragma unroll
        for (int ni = 0; ni < 2; ++ni)
          acc[mi][ni] = __builtin_amdgcn_mfma_f32_16x16x32_bf16(af[mi], bfr[ni], acc[mi][ni], 0, 0, 0);
    }
  }

  float* Pz = P + (size_t)blockIdx.z * M * N;
  const int r0 = (lane >> 4) * 4;
  const int cn = lane & 15;
#pragma unroll
  for (int mi = 0; mi < MI; ++mi) {
#pragma unroll
    for (int ni = 0; ni < 2; ++ni) {
      int n = n0 + wc * 32 + ni * 16 + cn;
#pragma unroll
      for (int r = 0; r < 4; ++r) {
        int m = m0 + wr * (BM / 2) + mi * 16 + r0 + r;
        Pz[(size_t)m * N + n] = acc[mi][ni][r];
      }
    }
  }
}

// ------- reduce_h3: sum 2 K-split slabs + bias -> relu -> split-bf16 -> H3
__global__ __launch_bounds__(256) void reduce_h3_kernel(
    const float* __restrict__ P, const float* __restrict__ bias,
    unsigned short* __restrict__ Hb) {
  const int M = 4096, N = 512;
  int g = blockIdx.x * 256 + threadIdx.x;   // 524288 threads
  int m = g >> 7;
  int n4 = (g & 127) << 2;
  const float* p = P + (size_t)m * N + n4;
  float4 v0 = *(const float4*)p;
  float4 v1 = *(const float4*)(p + (size_t)M * N);
  float4 vb = *(const float4*)(bias + n4);
  float r[4] = {v0.x + v1.x + vb.x, v0.y + v1.y + vb.y,
                v0.z + v1.z + vb.z, v0.w + v1.w + vb.w};
  u16x4 h4, l4;
#pragma unroll
  for (int i = 0; i < 4; ++i) {
    float v = fmaxf(r[i], 0.0f);
    unsigned short h = f2bf(v);
    h4[i] = h;
    l4[i] = f2bf(v - bf2f(h));
  }
  size_t rbase = (size_t)m * 1536;
  *(u16x4*)(Hb + rbase + n4)        = h4;
  *(u16x4*)(Hb + rbase + 512 + n4)  = h4;
  *(u16x4*)(Hb + rbase + 1024 + n4) = l4;
}

// ------- reduce_com: sum 4 K-split slabs + bias -> f32 com
__global__ __launch_bounds__(256) void reduce_com_kernel(
    const float* __restrict__ P, const float* __restrict__ bias,
    float* __restrict__ com) {
  const int M = 4096, N = 128;
  int g = blockIdx.x * 256 + threadIdx.x;   // 131072 threads
  int m = g >> 5;
  int n4 = (g & 31) << 2;
  const float* p = P + (size_t)m * N + n4;
  const size_t slab = (size_t)M * N;
  float4 a0 = *(const float4*)p;
  float4 a1 = *(const float4*)(p + slab);
  float4 a2 = *(const float4*)(p + 2 * slab);
  float4 a3 = *(const float4*)(p + 3 * slab);
  float4 vb = *(const float4*)(bias + n4);
  float4 r;
  r.x = a0.x + a1.x + a2.x + a3.x + vb.x;
  r.y = a0.y + a1.y + a2.y + a3.y + vb.y;
  r.z = a0.z + a1.z + a2.z + a3.z + vb.z;
  r.w = a0.w + a1.w + a2.w + a3.w + vb.w;
  *(float4*)(com + (size_t)m * N + n4) = r;
}

// ---------------- prep_gates: 48 gate matrices -> (g0,g1,g2,g3) table ---------
__global__ __launch_bounds__(64) void prep_gates(const float* __restrict__ asz,
                                                 float* __restrict__ gcoef) {
  int t = threadIdx.x;
  if (t < 48) {
    float phi = asz[t * 3 + 0], th = asz[t * 3 + 1], om = asz[t * 3 + 2];
    float sth, cth, sa, ca, sb, cb;
    sincosf(0.5f * th, &sth, &cth);
    sincosf(0.5f * (phi + om), &sa, &ca);
    sincosf(0.5f * (phi - om), &sb, &cb);
    float4 g;
    g.x =  ca * cth;   // g0 : Re m00 (= Re m11)
    g.y = -sa * cth;   // g1 : Im m00 (= -Im m11)
    g.z = -cb * sth;   // g2 : Re m01 (= -Re m10)
    g.w = -sb * sth;   // g3 : Im m01 (= Im m10)
    ((float4*)gcoef)[t] = g;
  }
}

// ---------------- quantum kernel: one block per batch item -------------------
__global__ __launch_bounds__(256) void quantum_kernel(
    const float* __restrict__ x, const float* __restrict__ com,
    const float* __restrict__ gcoef, float* __restrict__ out, QArgs qa) {
  __shared__ f32x2 st[4096];      // 32768 B
  __shared__ float xrow[2048];    //  8192 B  (total 40960 -> 4 blocks/CU)
  const int t = threadIdx.x;
  const int b = blockIdx.x;
  const float4* __restrict__ gc4 = (const float4*)gcoef;

  // stage x row (img angles); zero state
  {
    const float4* xs = (const float4*)(x + (size_t)b * 2048);
    ((float4*)xrow)[t] = xs[t];
    ((float4*)xrow)[t + 256] = xs[t + 256];
  }
#pragma unroll
  for (int s = 0; s < 16; ++s) st[s * 256 + t] = (f32x2){0.f, 0.f};
  __syncthreads();

  // init: H^{1..7} + FRQI(com,7): 256 real amps
  {
    int jj = t & 127, b0 = t >> 7;
    int p = __brev((unsigned)jj) >> 25;  // 7-bit reverse
    float ang = 0.5f * com[(size_t)b * 128 + p];
    float s = __sinf(ang), c = __cosf(ang);
    float val = (b0 ? s : c) * 0.08838834764831845f;  // 2^-3.5
    int j = (b0 << 11) | (jj << 4);
    *(f32x2*)((char*)st + (swz(j) << 3)) = (f32x2){val, 0.f};
  }
  __syncthreads();

  // 12 fused passes (4 Rot gates each), CNOTs folded into masks/roles
#pragma unroll 1
  for (int p = 0; p < 12; ++p) {
    // byte-swizzled coset base: srB = swz(rep)<<3, built per t-bit
    int srB = 0;
#pragma unroll
    for (int i = 0; i < 8; ++i) srB ^= ((t >> i) & 1) ? (int)qa.anp[p][i] : 0;

    // gate coefficients (wave-uniform loads) + per-thread role signs
    const int gi = (p / 3) * 12 + (p % 3) * 4;
    float4 gk0 = gc4[gi + 0], gk1 = gc4[gi + 1], gk2 = gc4[gi + 2], gk3 = gc4[gi + 3];
    unsigned sg0 = (unsigned)__popc(t & (int)qa.gm8[p][0]) << 31;
    unsigned sg1 = (unsigned)__popc(t & (int)qa.gm8[p][1]) << 31;
    unsigned sg2 = (unsigned)__popc(t & (int)qa.gm8[p][2]) << 31;
    unsigned sg3 = (unsigned)__popc(t & (int)qa.gm8[p][3]) << 31;

    int aB[16];
    f32x2 v[16];
#pragma unroll
    for (int s = 0; s < 16; ++s) {
      aB[s] = srB ^ (int)qa.xcs[p][s];
      v[s] = *(const f32x2*)((const char*)st + aB[s]);
    }

#pragma unroll
    for (int k = 0; k < 4; ++k) {
      float4 g = (k == 0) ? gk0 : (k == 1) ? gk1 : (k == 2) ? gk2 : gk3;
      unsigned sg = (k == 0) ? sg0 : (k == 1) ? sg1 : (k == 2) ? sg2 : sg3;
      f32x2 G0 = (f32x2)(g.x);
      f32x2 S1 = (f32x2)(xsign(g.y, sg));
      f32x2 S2 = (f32x2)(xsign(g.z, sg));
      f32x2 G3 = (f32x2)(g.w);
      const int bk = 1 << k;
#pragma unroll
      for (int s = 0; s < 16; ++s) {
        if (s & bk) continue;
        bfly(v[s], v[s | bk], G0, S1, S2, G3);
      }
    }
#pragma unroll
    for (int s = 0; s < 16; ++s) *(f32x2*)((char*)st + aB[s]) = v[s];
    __syncthreads();
  }

  // fused final FRQI(img,11) + readout:
  // per pair: |o1|^2-|o0|^2 = -(-1)^rho cos(x) (|a|^2-|b|^2) - 2 sin(x) <a,b>
  float accv = 0.f;
  {
    unsigned C0 = 0;
#pragma unroll
    for (int i = 0; i < 8; ++i) C0 ^= ((t >> i) & 1) ? qa.cmb_t[i] : 0u;
#pragma unroll
    for (int q = 0; q < 8; ++q) {
      unsigned C = C0 ^ qa.cmb_q[q];
      int aA = (int)(C & 0x7FF8u);
      int aB2 = aA ^ (int)qa.smF8;
      float ang = xrow[C >> 16];
      float sx = __sinf(ang), cx = __cosf(ang);
      f32x2 a = *(const f32x2*)((const char*)st + aA);
      f32x2 bb = *(const f32x2*)((const char*)st + aB2);
      float da = a.x * a.x + a.y * a.y;
      float db = bb.x * bb.x + bb.y * bb.y;
      float d = da - db;
      float dot = a.x * bb.x + a.y * bb.y;
      unsigned sgn = (C & 0x8000u) << 16;
      float dp = xsign(d, sgn);
      accv -= cx * dp + 2.0f * sx * dot;
    }
  }
  __syncthreads();   // all reads of st/xrow done before scratch reuse

  // reduce: wave shfl + cross-wave via xrow scratch
#pragma unroll
  for (int o = 32; o > 0; o >>= 1) accv += __shfl_down(accv, o, 64);
  if ((t & 63) == 0) xrow[t >> 6] = accv;
  __syncthreads();
  if (t == 0) out[b] = xrow[0] + xrow[1] + xrow[2] + xrow[3];
}

// ---------------------------------------------------------------------------
static inline int par16(int v) { return __builtin_popcount((unsigned)v) & 1; }

extern "C" void kernel_launch(void* const* d_in, const int* in_sizes, int n_in,
                              void* d_out, int out_size, void* d_ws, size_t ws_size,
                              hipStream_t stream) {
  (void)in_sizes; (void)n_in; (void)out_size; (void)ws_size;
  const float* x   = (const float*)d_in[0];
  const float* W1  = (const float*)d_in[1];
  const float* b1  = (const float*)d_in[2];
  const float* W2  = (const float*)d_in[3];
  const float* b2  = (const float*)d_in[4];
  const float* asz = (const float*)d_in[5];
  float* out = (float*)d_out;

  char* ws = (char*)d_ws;
  unsigned short* A3  = (unsigned short*)ws; ws += (size_t)4096 * 6144 * 2;
  unsigned short* B3T = (unsigned short*)ws; ws += (size_t)512 * 6144 * 2;
  unsigned short* H3  = (unsigned short*)ws; ws += (size_t)4096 * 1536 * 2;
  unsigned short* W23 = (unsigned short*)ws; ws += (size_t)128 * 1536 * 2;
  float* com = (float*)ws;                   ws += (size_t)4096 * 128 * 4;
  float* gcoef = (float*)ws;                 ws += (size_t)1024;
  float* P = (float*)ws;                     ws += (size_t)2 * 4096 * 512 * 4;  // 16.8 MB (aliased for gemm2's 4x4096x128)

  // ----- host: lazy CNOT tracking (circuit is input-independent) -----
  QArgs qa;
  int cols[12], rows[12];
  for (int w = 0; w < 12; ++w) cols[w] = rows[w] = 1 << (11 - w);
  int hswz;
  for (int l = 0; l < 4; ++l) {
    for (int g = 0; g < 3; ++g) {
      int p = l * 3 + g;
      int m[4], grow[4];
      for (int k = 0; k < 4; ++k) {
        int w = g * 4 + k;
        m[k] = cols[w];
        grow[k] = rows[w];
      }
      for (int s = 0; s < 16; ++s) {
        int v = 0;
        for (int k = 0; k < 4; ++k)
          if (s & (1 << k)) v ^= m[k];
        hswz = v ^ (v >> 5) ^ (v >> 10);
        qa.xcs[p][s] = (uint16_t)(hswz << 3);
      }
      int mm[4] = {m[0], m[1], m[2], m[3]};
      int piv = 0;
      for (int k = 0; k < 4; ++k) {
        int pb = 31 - __builtin_clz((unsigned)mm[k]);
        piv |= 1 << pb;
        for (int k2 = k + 1; k2 < 4; ++k2)
          if (mm[k2] & (1 << pb)) mm[k2] ^= mm[k];
      }
      int npb[8], c = 0;
      for (int bit = 0; bit < 12; ++bit)
        if (!(piv & (1 << bit))) npb[c++] = bit;
      for (int i = 0; i < 8; ++i) {
        int bv = 1 << npb[i];
        hswz = bv ^ (bv >> 5) ^ (bv >> 10);
        qa.anp[p][i] = (uint16_t)(hswz << 3);
      }
      for (int k = 0; k < 4; ++k) {
        int mask8 = 0;
        for (int i = 0; i < 8; ++i)
          mask8 |= ((grow[k] >> npb[i]) & 1) << i;
        qa.gm8[p][k] = (uint8_t)mask8;
      }
    }
    int r = l % 11 + 1;
    for (int w = 0; w < 12; ++w) {
      int cw = w, tw = (w + r) % 12;
      cols[cw] ^= cols[tw];   // A <- A o L (CNOT ctrl=w, tgt=(w+r)%12)
      rows[tw] ^= rows[cw];   // A^-1 <- L o A^-1
    }
  }
  // final FRQI fold: combined constants, all GF2-linear in u = (q<<8)|t
  {
    int mF = cols[0];
    int hb = 31 - __builtin_clz((unsigned)mF);
    int lowmask = (1 << hb) - 1;
    auto jAof = [&](int u) { return ((u & ~lowmask) << 1) | (u & lowmask); };
    auto cmbof = [&](int j) -> uint32_t {
      int pidx = 0;
      for (int w = 1; w < 12; ++w)
        pidx |= par16(j & rows[w]) << (w - 1);
      int rho = par16(j & rows[0]);
      int sj = j ^ (j >> 5) ^ (j >> 10);
      return ((uint32_t)pidx << 16) | ((uint32_t)rho << 15) | (uint32_t)(sj << 3);
    };
    for (int i = 0; i < 8; ++i) qa.cmb_t[i] = cmbof(jAof(1 << i));
    for (int q = 0; q < 8; ++q) qa.cmb_q[q] = cmbof(jAof(q << 8));
    int sF = mF ^ (mF >> 5) ^ (mF >> 10);
    qa.smF8 = (uint32_t)(sF << 3);
  }

  // ----- pipeline -----
  conv_x_kernel<<<4096, 256, 0, stream>>>(x, A3);
  conv_w_kernel<<<dim3(32, 8), 256, 0, stream>>>(W1, B3T, 2048, 512);
  conv_w_kernel<<<dim3(8, 2), 256, 0, stream>>>(W2, W23, 512, 128);
  prep_gates<<<1, 64, 0, stream>>>(asz, gcoef);
  gemm_part<64><<<dim3(64, 8, 2), 256, 0, stream>>>(A3, B3T, P, 4096, 512, 6144, 3072);
  reduce_h3_kernel<<<2048, 256, 0, stream>>>(P, b1, H3);
  gemm_part<64><<<dim3(64, 2, 4), 256, 0, stream>>>(H3, W23, P, 4096, 128, 1536, 384);
  reduce_com_kernel<<<512, 256, 0, stream>>>(P, b2, com);
  quantum_kernel<<<4096, 256, 0, stream>>>(x, com, gcoef, out, qa);
}

// Round 10
// 295.999 us; speedup vs baseline: 2.1517x; 1.5702x over previous
//
#include <hip/hip_runtime.h>
#include <stdint.h>
#include <math.h>

// ---------------------------------------------------------------------------
// HybridNN: MLP (split-bf16 MFMA GEMMs) + 12-qubit statevector circuit with
// lazy (GF2-linear) CNOT tracking and 4-gate-fused rotation passes.
// R10: gemm_part rewritten with fully NAMED registers (R9's lambda captured
// staging arrays by reference -> scratch spill -> 459MB HBM writes).
// ---------------------------------------------------------------------------

typedef __attribute__((ext_vector_type(4))) float f32x4;
typedef __attribute__((ext_vector_type(2))) float f32x2;
typedef __attribute__((ext_vector_type(8))) short bf16x8;
typedef __attribute__((ext_vector_type(8))) unsigned short u16x8;
typedef __attribute__((ext_vector_type(4))) unsigned short u16x4;

struct QArgs {
  uint16_t xcs[12][16];  // swz(xc)<<3 : byte-addr XOR combos of 4 gate masks
  uint16_t anp[12][8];   // swz(1<<np[i])<<3 : per-t-bit addr contribution
  uint8_t  gm8[12][4];   // rho over t bits: rho_k = popc(t & gm8)&1
  uint32_t cmb_t[8];     // final pass: (pidx<<16)|(rho<<15)|(swz(jA)<<3), t-bit i
  uint32_t cmb_q[8];     // same, q-bit contribution
  uint32_t smF8;         // swz(mF)<<3
};
static_assert(sizeof(QArgs) <= 1024, "kernarg too big");

__device__ __host__ __forceinline__ int swz(int j) { return j ^ (j >> 5) ^ (j >> 10); }

__device__ __forceinline__ unsigned short f2bf(float x) {
  unsigned u = __float_as_uint(x);
  unsigned r = (u + 0x7fffu + ((u >> 16) & 1u)) >> 16;  // RNE
  return (unsigned short)r;
}
__device__ __forceinline__ float bf2f(unsigned short h) {
  return __uint_as_float(((unsigned)h) << 16);
}
__device__ __forceinline__ float xsign(float v, unsigned sgn) {
  return __uint_as_float(__float_as_uint(v) ^ sgn);
}

// ---- packed dual-FP32 helpers (VOP3P). coef in src0, value in src1. ----
__device__ __forceinline__ f32x2 pkmul(f32x2 a, f32x2 b) {
  f32x2 d;
  asm("v_pk_mul_f32 %0, %1, %2" : "=v"(d) : "v"(a), "v"(b));
  return d;
}
__device__ __forceinline__ f32x2 pkfma(f32x2 a, f32x2 b, f32x2 c) {
  f32x2 d = c;
  asm("v_pk_fma_f32 %0, %1, %2, %0" : "+v"(d) : "v"(a), "v"(b));
  return d;
}
// value swapped (hi->lo, lo->hi), low product negated: (-a*b.hi, +a*b.lo)
__device__ __forceinline__ f32x2 pkfma_swapneglo(f32x2 a, f32x2 b, f32x2 c) {
  f32x2 d = c;
  asm("v_pk_fma_f32 %0, %1, %2, %0 op_sel:[0,1,0] op_sel_hi:[1,0,1] neg_lo:[0,1,0]"
      : "+v"(d) : "v"(a), "v"(b));
  return d;
}
// value swapped, high product negated: (+a*b.hi, -a*b.lo)
__device__ __forceinline__ f32x2 pkfma_swapneghi(f32x2 a, f32x2 b, f32x2 c) {
  f32x2 d = c;
  asm("v_pk_fma_f32 %0, %1, %2, %0 op_sel:[0,1,0] op_sel_hi:[1,0,1] neg_hi:[0,1,0]"
      : "+v"(d) : "v"(a), "v"(b));
  return d;
}
// both products negated: (-a*b.lo, -a*b.hi)
__device__ __forceinline__ f32x2 pkfma_negboth(f32x2 a, f32x2 b, f32x2 c) {
  f32x2 d = c;
  asm("v_pk_fma_f32 %0, %1, %2, %0 neg_lo:[0,1,0] neg_hi:[0,1,0]"
      : "+v"(d) : "v"(a), "v"(b));
  return d;
}

// complex 2x2 rotation butterfly on packed (re,im) amps A,B
__device__ __forceinline__ void bfly(f32x2& A, f32x2& B,
                                     f32x2 G0, f32x2 S1, f32x2 S2, f32x2 G3) {
  f32x2 na = pkmul(G0, A);
  na = pkfma_swapneglo(S1, A, na);
  na = pkfma(S2, B, na);
  na = pkfma_swapneglo(G3, B, na);
  f32x2 nb = pkmul(G0, B);
  nb = pkfma_swapneghi(S1, B, nb);
  nb = pkfma_negboth(S2, A, nb);
  nb = pkfma_swapneglo(G3, A, nb);
  A = na;
  B = nb;
}

// ---------------- conv_x: x (4096x2048 f32) -> A3 = [hi|hi|lo] bf16 (4096x6144)
__global__ __launch_bounds__(256) void conv_x_kernel(const float* __restrict__ x,
                                                     unsigned short* __restrict__ A3) {
  int g = blockIdx.x * 256 + threadIdx.x;   // 1,048,576 threads
  int m = g >> 8;
  int c8 = (g & 255) << 3;
  const float4* src = (const float4*)(x + (size_t)m * 2048 + c8);
  float4 v0 = src[0], v1 = src[1];
  float vs[8] = {v0.x, v0.y, v0.z, v0.w, v1.x, v1.y, v1.z, v1.w};
  u16x8 h8, l8;
#pragma unroll
  for (int i = 0; i < 8; ++i) {
    unsigned short h = f2bf(vs[i]);
    h8[i] = h;
    l8[i] = f2bf(vs[i] - bf2f(h));
  }
  size_t base = (size_t)m * 6144 + c8;
  *(u16x8*)(A3 + base)        = h8;
  *(u16x8*)(A3 + base + 2048) = h8;
  *(u16x8*)(A3 + base + 4096) = l8;
}

// ------------- conv_w: W (KxN f32, row-major) -> BT = N x 3K bf16, segs [hi|lo|hi]
__global__ __launch_bounds__(256) void conv_w_kernel(const float* __restrict__ W,
                                                     unsigned short* __restrict__ BT,
                                                     int K, int N) {
  __shared__ float tile[64][65];
  int k0 = blockIdx.x * 64, n0 = blockIdx.y * 64;
  int t = threadIdx.x;
  int li = t >> 2;             // 0..63
  int lj = (t & 3) << 4;       // 0,16,32,48
  const float* src = W + (size_t)(k0 + li) * N + n0 + lj;
#pragma unroll
  for (int c = 0; c < 16; c += 4) {
    float4 v = *(const float4*)(src + c);
    tile[li][lj + c + 0] = v.x; tile[li][lj + c + 1] = v.y;
    tile[li][lj + c + 2] = v.z; tile[li][lj + c + 3] = v.w;
  }
  __syncthreads();
  int n = n0 + li;
  int kk = lj;
  u16x8 hi2[2], lo2[2];
#pragma unroll
  for (int c = 0; c < 16; ++c) {
    float v = tile[kk + c][li];
    unsigned short h = f2bf(v);
    hi2[c >> 3][c & 7] = h;
    lo2[c >> 3][c & 7] = f2bf(v - bf2f(h));
  }
  size_t rb = (size_t)n * (3 * (size_t)K) + k0 + kk;
  *(u16x8*)(BT + rb)         = hi2[0];
  *(u16x8*)(BT + rb + 8)     = hi2[1];
  *(u16x8*)(BT + rb + K)     = lo2[0];
  *(u16x8*)(BT + rb + K + 8) = lo2[1];
  *(u16x8*)(BT + rb + 2*K)     = hi2[0];
  *(u16x8*)(BT + rb + 2*K + 8) = hi2[1];
}

// ---------------- MFMA GEMM partial: P[z] = A(MxK-slice) * B^T(NxK-slice)
// BM=64 fixed; all staging state in NAMED registers (no arrays, no lambdas).
__global__ __launch_bounds__(256) void gemm_part(
    const unsigned short* __restrict__ A, const unsigned short* __restrict__ B,
    float* __restrict__ P, int M, int N, int K, int KS) {
  constexpr int BK = 64;
  __shared__ unsigned short smA[64 * BK];
  __shared__ unsigned short smB[64 * BK];
  const int t = threadIdx.x, wave = t >> 6, lane = t & 63;
  const int m0 = blockIdx.x * 64, n0 = blockIdx.y * 64;
  const int k0 = blockIdx.z * KS, k1 = k0 + KS;
  const int wr = wave >> 1, wc = wave & 1;

  f32x4 acc00 = (f32x4)0.f, acc01 = (f32x4)0.f;
  f32x4 acc10 = (f32x4)0.f, acc11 = (f32x4)0.f;

  // staging geometry, fully scalarized
  const int off0 = t * 16, off1 = (256 + t) * 16;
  const int ar0 = off0 >> 7, ac0 = off0 & 127;
  const int ar1 = off1 >> 7, ac1 = off1 & 127;
  const int ad0 = off0 ^ ((ar0 & 7) << 4);
  const int ad1 = off1 ^ ((ar1 & 7) << 4);
  const char* Ab0 = (const char*)A + ((size_t)(m0 + ar0) * K) * 2 + ac0;
  const char* Ab1 = (const char*)A + ((size_t)(m0 + ar1) * K) * 2 + ac1;
  const char* Bb0 = (const char*)B + ((size_t)(n0 + ar0) * K) * 2 + ac0;
  const char* Bb1 = (const char*)B + ((size_t)(n0 + ar1) * K) * 2 + ac1;

  // LDS read offsets (per-thread constants)
  const int la = lane & 15;
  const int kb0 = (lane >> 4) * 16;           // kk=0 byte base
  const int rA0 = wr * 32 + la,      rA1 = wr * 32 + 16 + la;
  const int rB0 = wc * 32 + la,      rB1 = wc * 32 + 16 + la;
  const int oA0 = (rA0 * 128 + kb0) ^ ((rA0 & 7) << 4);
  const int oA1 = (rA1 * 128 + kb0) ^ ((rA1 & 7) << 4);
  const int oB0 = (rB0 * 128 + kb0) ^ ((rB0 & 7) << 4);
  const int oB1 = (rB1 * 128 + kb0) ^ ((rB1 & 7) << 4);

  uint4 ra0 = *(const uint4*)(Ab0 + (size_t)k0 * 2);
  uint4 ra1 = *(const uint4*)(Ab1 + (size_t)k0 * 2);
  uint4 rb0 = *(const uint4*)(Bb0 + (size_t)k0 * 2);
  uint4 rb1 = *(const uint4*)(Bb1 + (size_t)k0 * 2);

  for (int kt = k0; kt < k1; kt += BK) {
    __syncthreads();           // previous tile's readers done
    *(uint4*)((char*)smA + ad0) = ra0;
    *(uint4*)((char*)smA + ad1) = ra1;
    *(uint4*)((char*)smB + ad0) = rb0;
    *(uint4*)((char*)smB + ad1) = rb1;
    __syncthreads();           // tile visible
    const int ktn = kt + BK;
    if (ktn < k1) {            // prefetch next tile (in flight across MFMA)
      ra0 = *(const uint4*)(Ab0 + (size_t)ktn * 2);
      ra1 = *(const uint4*)(Ab1 + (size_t)ktn * 2);
      rb0 = *(const uint4*)(Bb0 + (size_t)ktn * 2);
      rb1 = *(const uint4*)(Bb1 + (size_t)ktn * 2);
    }
#pragma unroll
    for (int kk = 0; kk < 2; ++kk) {
      const int kb = kk * 64;
      bf16x8 af0 = *(const bf16x8*)((const char*)smA + (oA0 ^ kb));
      bf16x8 af1 = *(const bf16x8*)((const char*)smA + (oA1 ^ kb));
      bf16x8 bf0 = *(const bf16x8*)((const char*)smB + (oB0 ^ kb));
      bf16x8 bf1 = *(const bf16x8*)((const char*)smB + (oB1 ^ kb));
      acc00 = __builtin_amdgcn_mfma_f32_16x16x32_bf16(af0, bf0, acc00, 0, 0, 0);
      acc01 = __builtin_amdgcn_mfma_f32_16x16x32_bf16(af0, bf1, acc01, 0, 0, 0);
      acc10 = __builtin_amdgcn_mfma_f32_16x16x32_bf16(af1, bf0, acc10, 0, 0, 0);
      acc11 = __builtin_amdgcn_mfma_f32_16x16x32_bf16(af1, bf1, acc11, 0, 0, 0);
    }
  }

  float* Pz = P + (size_t)blockIdx.z * M * N;
  const int r0 = (lane >> 4) * 4;
  const int cn = lane & 15;
  const int mA = m0 + wr * 32 + r0;
  const int nA = n0 + wc * 32 + cn;
#pragma unroll
  for (int r = 0; r < 4; ++r) {
    Pz[(size_t)(mA + r) * N + nA]           = acc00[r];
    Pz[(size_t)(mA + r) * N + nA + 16]      = acc01[r];
    Pz[(size_t)(mA + 16 + r) * N + nA]      = acc10[r];
    Pz[(size_t)(mA + 16 + r) * N + nA + 16] = acc11[r];
  }
}

// ------- reduce_h3: sum 2 K-split slabs + bias -> relu -> split-bf16 -> H3
__global__ __launch_bounds__(256) void reduce_h3_kernel(
    const float* __restrict__ P, const float* __restrict__ bias,
    unsigned short* __restrict__ Hb) {
  const int M = 4096, N = 512;
  int g = blockIdx.x * 256 + threadIdx.x;   // 524288 threads
  int m = g >> 7;
  int n4 = (g & 127) << 2;
  const float* p = P + (size_t)m * N + n4;
  float4 v0 = *(const float4*)p;
  float4 v1 = *(const float4*)(p + (size_t)M * N);
  float4 vb = *(const float4*)(bias + n4);
  float r[4] = {v0.x + v1.x + vb.x, v0.y + v1.y + vb.y,
                v0.z + v1.z + vb.z, v0.w + v1.w + vb.w};
  u16x4 h4, l4;
#pragma unroll
  for (int i = 0; i < 4; ++i) {
    float v = fmaxf(r[i], 0.0f);
    unsigned short h = f2bf(v);
    h4[i] = h;
    l4[i] = f2bf(v - bf2f(h));
  }
  size_t rbase = (size_t)m * 1536;
  *(u16x4*)(Hb + rbase + n4)        = h4;
  *(u16x4*)(Hb + rbase + 512 + n4)  = h4;
  *(u16x4*)(Hb + rbase + 1024 + n4) = l4;
}

// ------- reduce_com: sum 4 K-split slabs + bias -> f32 com
__global__ __launch_bounds__(256) void reduce_com_kernel(
    const float* __restrict__ P, const float* __restrict__ bias,
    float* __restrict__ com) {
  const int M = 4096, N = 128;
  int g = blockIdx.x * 256 + threadIdx.x;   // 131072 threads
  int m = g >> 5;
  int n4 = (g & 31) << 2;
  const float* p = P + (size_t)m * N + n4;
  const size_t slab = (size_t)M * N;
  float4 a0 = *(const float4*)p;
  float4 a1 = *(const float4*)(p + slab);
  float4 a2 = *(const float4*)(p + 2 * slab);
  float4 a3 = *(const float4*)(p + 3 * slab);
  float4 vb = *(const float4*)(bias + n4);
  float4 r;
  r.x = a0.x + a1.x + a2.x + a3.x + vb.x;
  r.y = a0.y + a1.y + a2.y + a3.y + vb.y;
  r.z = a0.z + a1.z + a2.z + a3.z + vb.z;
  r.w = a0.w + a1.w + a2.w + a3.w + vb.w;
  *(float4*)(com + (size_t)m * N + n4) = r;
}

// ---------------- prep_gates: 48 gate matrices -> (g0,g1,g2,g3) table ---------
__global__ __launch_bounds__(64) void prep_gates(const float* __restrict__ asz,
                                                 float* __restrict__ gcoef) {
  int t = threadIdx.x;
  if (t < 48) {
    float phi = asz[t * 3 + 0], th = asz[t * 3 + 1], om = asz[t * 3 + 2];
    float sth, cth, sa, ca, sb, cb;
    sincosf(0.5f * th, &sth, &cth);
    sincosf(0.5f * (phi + om), &sa, &ca);
    sincosf(0.5f * (phi - om), &sb, &cb);
    float4 g;
    g.x =  ca * cth;   // g0 : Re m00 (= Re m11)
    g.y = -sa * cth;   // g1 : Im m00 (= -Im m11)
    g.z = -cb * sth;   // g2 : Re m01 (= -Re m10)
    g.w = -sb * sth;   // g3 : Im m01 (= Im m10)
    ((float4*)gcoef)[t] = g;
  }
}

// ---------------- quantum kernel: one block per batch item -------------------
__global__ __launch_bounds__(256) void quantum_kernel(
    const float* __restrict__ x, const float* __restrict__ com,
    const float* __restrict__ gcoef, float* __restrict__ out, QArgs qa) {
  __shared__ f32x2 st[4096];      // 32768 B
  __shared__ float xrow[2048];    //  8192 B  (total 40960 -> 4 blocks/CU)
  const int t = threadIdx.x;
  const int b = blockIdx.x;
  const float4* __restrict__ gc4 = (const float4*)gcoef;

  // stage x row (img angles); zero state
  {
    const float4* xs = (const float4*)(x + (size_t)b * 2048);
    ((float4*)xrow)[t] = xs[t];
    ((float4*)xrow)[t + 256] = xs[t + 256];
  }
#pragma unroll
  for (int s = 0; s < 16; ++s) st[s * 256 + t] = (f32x2){0.f, 0.f};
  __syncthreads();

  // init: H^{1..7} + FRQI(com,7): 256 real amps
  {
    int jj = t & 127, b0 = t >> 7;
    int p = __brev((unsigned)jj) >> 25;  // 7-bit reverse
    float ang = 0.5f * com[(size_t)b * 128 + p];
    float s = __sinf(ang), c = __cosf(ang);
    float val = (b0 ? s : c) * 0.08838834764831845f;  // 2^-3.5
    int j = (b0 << 11) | (jj << 4);
    *(f32x2*)((char*)st + (swz(j) << 3)) = (f32x2){val, 0.f};
  }
  __syncthreads();

  // 12 fused passes (4 Rot gates each), CNOTs folded into masks/roles
#pragma unroll 1
  for (int p = 0; p < 12; ++p) {
    // byte-swizzled coset base: srB = swz(rep)<<3, built per t-bit
    int srB = 0;
#pragma unroll
    for (int i = 0; i < 8; ++i) srB ^= ((t >> i) & 1) ? (int)qa.anp[p][i] : 0;

    // gate coefficients (wave-uniform loads) + per-thread role signs
    const int gi = (p / 3) * 12 + (p % 3) * 4;
    float4 gk0 = gc4[gi + 0], gk1 = gc4[gi + 1], gk2 = gc4[gi + 2], gk3 = gc4[gi + 3];
    unsigned sg0 = (unsigned)__popc(t & (int)qa.gm8[p][0]) << 31;
    unsigned sg1 = (unsigned)__popc(t & (int)qa.gm8[p][1]) << 31;
    unsigned sg2 = (unsigned)__popc(t & (int)qa.gm8[p][2]) << 31;
    unsigned sg3 = (unsigned)__popc(t & (int)qa.gm8[p][3]) << 31;

    int aB[16];
    f32x2 v[16];
#pragma unroll
    for (int s = 0; s < 16; ++s) {
      aB[s] = srB ^ (int)qa.xcs[p][s];
      v[s] = *(const f32x2*)((const char*)st + aB[s]);
    }

#pragma unroll
    for (int k = 0; k < 4; ++k) {
      float4 g = (k == 0) ? gk0 : (k == 1) ? gk1 : (k == 2) ? gk2 : gk3;
      unsigned sg = (k == 0) ? sg0 : (k == 1) ? sg1 : (k == 2) ? sg2 : sg3;
      f32x2 G0 = (f32x2)(g.x);
      f32x2 S1 = (f32x2)(xsign(g.y, sg));
      f32x2 S2 = (f32x2)(xsign(g.z, sg));
      f32x2 G3 = (f32x2)(g.w);
      const int bk = 1 << k;
#pragma unroll
      for (int s = 0; s < 16; ++s) {
        if (s & bk) continue;
        bfly(v[s], v[s | bk], G0, S1, S2, G3);
      }
    }
#pragma unroll
    for (int s = 0; s < 16; ++s) *(f32x2*)((char*)st + aB[s]) = v[s];
    __syncthreads();
  }

  // fused final FRQI(img,11) + readout:
  // per pair: |o1|^2-|o0|^2 = -(-1)^rho cos(x) (|a|^2-|b|^2) - 2 sin(x) <a,b>
  float accv = 0.f;
  {
    unsigned C0 = 0;
#pragma unroll
    for (int i = 0; i < 8; ++i) C0 ^= ((t >> i) & 1) ? qa.cmb_t[i] : 0u;
#pragma unroll
    for (int q = 0; q < 8; ++q) {
      unsigned C = C0 ^ qa.cmb_q[q];
      int aA = (int)(C & 0x7FF8u);
      int aB2 = aA ^ (int)qa.smF8;
      float ang = xrow[C >> 16];
      float sx = __sinf(ang), cx = __cosf(ang);
      f32x2 a = *(const f32x2*)((const char*)st + aA);
      f32x2 bb = *(const f32x2*)((const char*)st + aB2);
      float da = a.x * a.x + a.y * a.y;
      float db = bb.x * bb.x + bb.y * bb.y;
      float d = da - db;
      float dot = a.x * bb.x + a.y * bb.y;
      unsigned sgn = (C & 0x8000u) << 16;
      float dp = xsign(d, sgn);
      accv -= cx * dp + 2.0f * sx * dot;
    }
  }
  __syncthreads();   // all reads of st/xrow done before scratch reuse

  // reduce: wave shfl + cross-wave via xrow scratch
#pragma unroll
  for (int o = 32; o > 0; o >>= 1) accv += __shfl_down(accv, o, 64);
  if ((t & 63) == 0) xrow[t >> 6] = accv;
  __syncthreads();
  if (t == 0) out[b] = xrow[0] + xrow[1] + xrow[2] + xrow[3];
}

// ---------------------------------------------------------------------------
static inline int par16(int v) { return __builtin_popcount((unsigned)v) & 1; }

extern "C" void kernel_launch(void* const* d_in, const int* in_sizes, int n_in,
                              void* d_out, int out_size, void* d_ws, size_t ws_size,
                              hipStream_t stream) {
  (void)in_sizes; (void)n_in; (void)out_size; (void)ws_size;
  const float* x   = (const float*)d_in[0];
  const float* W1  = (const float*)d_in[1];
  const float* b1  = (const float*)d_in[2];
  const float* W2  = (const float*)d_in[3];
  const float* b2  = (const float*)d_in[4];
  const float* asz = (const float*)d_in[5];
  float* out = (float*)d_out;

  char* ws = (char*)d_ws;
  unsigned short* A3  = (unsigned short*)ws; ws += (size_t)4096 * 6144 * 2;
  unsigned short* B3T = (unsigned short*)ws; ws += (size_t)512 * 6144 * 2;
  unsigned short* H3  = (unsigned short*)ws; ws += (size_t)4096 * 1536 * 2;
  unsigned short* W23 = (unsigned short*)ws; ws += (size_t)128 * 1536 * 2;
  float* com = (float*)ws;                   ws += (size_t)4096 * 128 * 4;
  float* gcoef = (float*)ws;                 ws += (size_t)1024;
  float* P = (float*)ws;                     ws += (size_t)2 * 4096 * 512 * 4;  // 16.8 MB (aliased for gemm2's 4x4096x128)

  // ----- host: lazy CNOT tracking (circuit is input-independent) -----
  QArgs qa;
  int cols[12], rows[12];
  for (int w = 0; w < 12; ++w) cols[w] = rows[w] = 1 << (11 - w);
  int hswz;
  for (int l = 0; l < 4; ++l) {
    for (int g = 0; g < 3; ++g) {
      int p = l * 3 + g;
      int m[4], grow[4];
      for (int k = 0; k < 4; ++k) {
        int w = g * 4 + k;
        m[k] = cols[w];
        grow[k] = rows[w];
      }
      for (int s = 0; s < 16; ++s) {
        int v = 0;
        for (int k = 0; k < 4; ++k)
          if (s & (1 << k)) v ^= m[k];
        hswz = v ^ (v >> 5) ^ (v >> 10);
        qa.xcs[p][s] = (uint16_t)(hswz << 3);
      }
      int mm[4] = {m[0], m[1], m[2], m[3]};
      int piv = 0;
      for (int k = 0; k < 4; ++k) {
        int pb = 31 - __builtin_clz((unsigned)mm[k]);
        piv |= 1 << pb;
        for (int k2 = k + 1; k2 < 4; ++k2)
          if (mm[k2] & (1 << pb)) mm[k2] ^= mm[k];
      }
      int npb[8], c = 0;
      for (int bit = 0; bit < 12; ++bit)
        if (!(piv & (1 << bit))) npb[c++] = bit;
      for (int i = 0; i < 8; ++i) {
        int bv = 1 << npb[i];
        hswz = bv ^ (bv >> 5) ^ (bv >> 10);
        qa.anp[p][i] = (uint16_t)(hswz << 3);
      }
      for (int k = 0; k < 4; ++k) {
        int mask8 = 0;
        for (int i = 0; i < 8; ++i)
          mask8 |= ((grow[k] >> npb[i]) & 1) << i;
        qa.gm8[p][k] = (uint8_t)mask8;
      }
    }
    int r = l % 11 + 1;
    for (int w = 0; w < 12; ++w) {
      int cw = w, tw = (w + r) % 12;
      cols[cw] ^= cols[tw];   // A <- A o L (CNOT ctrl=w, tgt=(w+r)%12)
      rows[tw] ^= rows[cw];   // A^-1 <- L o A^-1
    }
  }
  // final FRQI fold: combined constants, all GF2-linear in u = (q<<8)|t
  {
    int mF = cols[0];
    int hb = 31 - __builtin_clz((unsigned)mF);
    int lowmask = (1 << hb) - 1;
    auto jAof = [&](int u) { return ((u & ~lowmask) << 1) | (u & lowmask); };
    auto cmbof = [&](int j) -> uint32_t {
      int pidx = 0;
      for (int w = 1; w < 12; ++w)
        pidx |= par16(j & rows[w]) << (w - 1);
      int rho = par16(j & rows[0]);
      int sj = j ^ (j >> 5) ^ (j >> 10);
      return ((uint32_t)pidx << 16) | ((uint32_t)rho << 15) | (uint32_t)(sj << 3);
    };
    for (int i = 0; i < 8; ++i) qa.cmb_t[i] = cmbof(jAof(1 << i));
    for (int q = 0; q < 8; ++q) qa.cmb_q[q] = cmbof(jAof(q << 8));
    int sF = mF ^ (mF >> 5) ^ (mF >> 10);
    qa.smF8 = (uint32_t)(sF << 3);
  }

  // ----- pipeline -----
  conv_x_kernel<<<4096, 256, 0, stream>>>(x, A3);
  conv_w_kernel<<<dim3(32, 8), 256, 0, stream>>>(W1, B3T, 2048, 512);
  conv_w_kernel<<<dim3(8, 2), 256, 0, stream>>>(W2, W23, 512, 128);
  prep_gates<<<1, 64, 0, stream>>>(asz, gcoef);
  gemm_part<<<dim3(64, 8, 2), 256, 0, stream>>>(A3, B3T, P, 4096, 512, 6144, 3072);
  reduce_h3_kernel<<<2048, 256, 0, stream>>>(P, b1, H3);
  gemm_part<<<dim3(64, 2, 4), 256, 0, stream>>>(H3, W23, P, 4096, 128, 1536, 384);
  reduce_com_kernel<<<512, 256, 0, stream>>>(P, b2, com);
  quantum_kernel<<<4096, 256, 0, stream>>>(x, com, gcoef, out, qa);
}

// Round 12
// 291.604 us; speedup vs baseline: 2.1842x; 1.0151x over previous
//
#include <hip/hip_runtime.h>
#include <stdint.h>
#include <math.h>

// ---------------------------------------------------------------------------
// HybridNN: MLP (split-bf16 MFMA GEMMs) + 12-qubit statevector circuit with
// lazy (GF2-linear) CNOT tracking and 4-gate-fused rotation passes.
// R11/R12: gemm1 -> 128x128 tile, 4 waves, 4x4 frags/wave, global_load_lds(16B)
// staging with pre-swizzled global source (linear LDS dest, swizzled reads).
// ---------------------------------------------------------------------------

typedef __attribute__((ext_vector_type(4))) float f32x4;
typedef __attribute__((ext_vector_type(2))) float f32x2;
typedef __attribute__((ext_vector_type(8))) short bf16x8;
typedef __attribute__((ext_vector_type(8))) unsigned short u16x8;
typedef __attribute__((ext_vector_type(4))) unsigned short u16x4;

struct QArgs {
  uint16_t xcs[12][16];  // swz(xc)<<3 : byte-addr XOR combos of 4 gate masks
  uint16_t anp[12][8];   // swz(1<<np[i])<<3 : per-t-bit addr contribution
  uint8_t  gm8[12][4];   // rho over t bits: rho_k = popc(t & gm8)&1
  uint32_t cmb_t[8];     // final pass: (pidx<<16)|(rho<<15)|(swz(jA)<<3), t-bit i
  uint32_t cmb_q[8];     // same, q-bit contribution
  uint32_t smF8;         // swz(mF)<<3
};
static_assert(sizeof(QArgs) <= 1024, "kernarg too big");

__device__ __host__ __forceinline__ int swz(int j) { return j ^ (j >> 5) ^ (j >> 10); }

__device__ __forceinline__ unsigned short f2bf(float x) {
  unsigned u = __float_as_uint(x);
  unsigned r = (u + 0x7fffu + ((u >> 16) & 1u)) >> 16;  // RNE
  return (unsigned short)r;
}
__device__ __forceinline__ float bf2f(unsigned short h) {
  return __uint_as_float(((unsigned)h) << 16);
}
__device__ __forceinline__ float xsign(float v, unsigned sgn) {
  return __uint_as_float(__float_as_uint(v) ^ sgn);
}

// ---- packed dual-FP32 helpers (VOP3P). coef in src0, value in src1. ----
__device__ __forceinline__ f32x2 pkmul(f32x2 a, f32x2 b) {
  f32x2 d;
  asm("v_pk_mul_f32 %0, %1, %2" : "=v"(d) : "v"(a), "v"(b));
  return d;
}
__device__ __forceinline__ f32x2 pkfma(f32x2 a, f32x2 b, f32x2 c) {
  f32x2 d = c;
  asm("v_pk_fma_f32 %0, %1, %2, %0" : "+v"(d) : "v"(a), "v"(b));
  return d;
}
// value swapped (hi->lo, lo->hi), low product negated: (-a*b.hi, +a*b.lo)
__device__ __forceinline__ f32x2 pkfma_swapneglo(f32x2 a, f32x2 b, f32x2 c) {
  f32x2 d = c;
  asm("v_pk_fma_f32 %0, %1, %2, %0 op_sel:[0,1,0] op_sel_hi:[1,0,1] neg_lo:[0,1,0]"
      : "+v"(d) : "v"(a), "v"(b));
  return d;
}
// value swapped, high product negated: (+a*b.hi, -a*b.lo)
__device__ __forceinline__ f32x2 pkfma_swapneghi(f32x2 a, f32x2 b, f32x2 c) {
  f32x2 d = c;
  asm("v_pk_fma_f32 %0, %1, %2, %0 op_sel:[0,1,0] op_sel_hi:[1,0,1] neg_hi:[0,1,0]"
      : "+v"(d) : "v"(a), "v"(b));
  return d;
}
// both products negated: (-a*b.lo, -a*b.hi)
__device__ __forceinline__ f32x2 pkfma_negboth(f32x2 a, f32x2 b, f32x2 c) {
  f32x2 d = c;
  asm("v_pk_fma_f32 %0, %1, %2, %0 neg_lo:[0,1,0] neg_hi:[0,1,0]"
      : "+v"(d) : "v"(a), "v"(b));
  return d;
}

// complex 2x2 rotation butterfly on packed (re,im) amps A,B
__device__ __forceinline__ void bfly(f32x2& A, f32x2& B,
                                     f32x2 G0, f32x2 S1, f32x2 S2, f32x2 G3) {
  f32x2 na = pkmul(G0, A);
  na = pkfma_swapneglo(S1, A, na);
  na = pkfma(S2, B, na);
  na = pkfma_swapneglo(G3, B, na);
  f32x2 nb = pkmul(G0, B);
  nb = pkfma_swapneghi(S1, B, nb);
  nb = pkfma_negboth(S2, A, nb);
  nb = pkfma_swapneglo(G3, A, nb);
  A = na;
  B = nb;
}

// ---------------- conv_x: x (4096x2048 f32) -> A3 = [hi|hi|lo] bf16 (4096x6144)
__global__ __launch_bounds__(256) void conv_x_kernel(const float* __restrict__ x,
                                                     unsigned short* __restrict__ A3) {
  int g = blockIdx.x * 256 + threadIdx.x;   // 1,048,576 threads
  int m = g >> 8;
  int c8 = (g & 255) << 3;
  const float4* src = (const float4*)(x + (size_t)m * 2048 + c8);
  float4 v0 = src[0], v1 = src[1];
  float vs[8] = {v0.x, v0.y, v0.z, v0.w, v1.x, v1.y, v1.z, v1.w};
  u16x8 h8, l8;
#pragma unroll
  for (int i = 0; i < 8; ++i) {
    unsigned short h = f2bf(vs[i]);
    h8[i] = h;
    l8[i] = f2bf(vs[i] - bf2f(h));
  }
  size_t base = (size_t)m * 6144 + c8;
  *(u16x8*)(A3 + base)        = h8;
  *(u16x8*)(A3 + base + 2048) = h8;
  *(u16x8*)(A3 + base + 4096) = l8;
}

// ------------- conv_w: W (KxN f32, row-major) -> BT = N x 3K bf16, segs [hi|lo|hi]
__global__ __launch_bounds__(256) void conv_w_kernel(const float* __restrict__ W,
                                                     unsigned short* __restrict__ BT,
                                                     int K, int N) {
  __shared__ float tile[64][65];
  int k0 = blockIdx.x * 64, n0 = blockIdx.y * 64;
  int t = threadIdx.x;
  int li = t >> 2;             // 0..63
  int lj = (t & 3) << 4;       // 0,16,32,48
  const float* src = W + (size_t)(k0 + li) * N + n0 + lj;
#pragma unroll
  for (int c = 0; c < 16; c += 4) {
    float4 v = *(const float4*)(src + c);
    tile[li][lj + c + 0] = v.x; tile[li][lj + c + 1] = v.y;
    tile[li][lj + c + 2] = v.z; tile[li][lj + c + 3] = v.w;
  }
  __syncthreads();
  int n = n0 + li;
  int kk = lj;
  u16x8 hi2[2], lo2[2];
#pragma unroll
  for (int c = 0; c < 16; ++c) {
    float v = tile[kk + c][li];
    unsigned short h = f2bf(v);
    hi2[c >> 3][c & 7] = h;
    lo2[c >> 3][c & 7] = f2bf(v - bf2f(h));
  }
  size_t rb = (size_t)n * (3 * (size_t)K) + k0 + kk;
  *(u16x8*)(BT + rb)         = hi2[0];
  *(u16x8*)(BT + rb + 8)     = hi2[1];
  *(u16x8*)(BT + rb + K)     = lo2[0];
  *(u16x8*)(BT + rb + K + 8) = lo2[1];
  *(u16x8*)(BT + rb + 2*K)     = hi2[0];
  *(u16x8*)(BT + rb + 2*K + 8) = hi2[1];
}

// ---------------- gemm128: P[z] = A(128-rows x K-slice) * B^T(128-rows x K-slice)
// 256 thr / 4 waves, wave owns 64x64 (4x4 16-tiles). global_load_lds 16B staging,
// LINEAR LDS dest + XOR-pre-swizzled GLOBAL source + swizzled ds_read (rule-21).
__global__ __launch_bounds__(256) void gemm128(
    const unsigned short* __restrict__ A, const unsigned short* __restrict__ B,
    float* __restrict__ P, int M, int N, int K, int KS) {
  constexpr int BK = 64;
  __shared__ unsigned short smA[128 * BK];   // 16 KB, [row][64 bf16] linear
  __shared__ unsigned short smB[128 * BK];   // 16 KB
  const int t = threadIdx.x, wave = t >> 6, lane = t & 63;
  const int m0 = blockIdx.x * 128, n0 = blockIdx.y * 128;
  const int k0 = blockIdx.z * KS, k1 = k0 + KS;
  const int wr = wave >> 1, wc = wave & 1;

  f32x4 acc[4][4];
#pragma unroll
  for (int i = 0; i < 4; ++i)
#pragma unroll
    for (int j = 0; j < 4; ++j) acc[i][j] = (f32x4)0.0f;

  // staging: issue i covers rows i*32 + (t>>3); chunk = (t&7) XOR (row&7) [src-swz]
  const int rsub = t >> 3;                 // 0..31
  const int csw = ((t & 7) ^ (rsub & 7)) * 8;  // element offset (pre-swizzled)
  // LDS dest: wave-uniform base; lane l lands at base + l*16
  const int ldsoff = wave * 1024;          // + i*4096

  // frag read offsets (swizzled): row*128 + ((q + 4*kk) ^ (row&7))*16
  const int q = lane >> 4, la = lane & 15;

  for (int kt = k0; kt < k1; kt += BK) {
#pragma unroll
    for (int i = 0; i < 4; ++i) {
      int row = i * 32 + rsub;
      const unsigned short* ga = A + (size_t)(m0 + row) * K + kt + csw;
      __builtin_amdgcn_global_load_lds(
          (const __attribute__((address_space(1))) unsigned int*)ga,
          (__attribute__((address_space(3))) unsigned int*)((char*)smA + i * 4096 + ldsoff),
          16, 0, 0);
    }
#pragma unroll
    for (int i = 0; i < 4; ++i) {
      int row = i * 32 + rsub;
      const unsigned short* gb = B + (size_t)(n0 + row) * K + kt + csw;
      __builtin_amdgcn_global_load_lds(
          (const __attribute__((address_space(1))) unsigned int*)gb,
          (__attribute__((address_space(3))) unsigned int*)((char*)smB + i * 4096 + ldsoff),
          16, 0, 0);
    }
    __syncthreads();   // drains vmcnt -> tile visible

#pragma unroll
    for (int kk = 0; kk < 2; ++kk) {
      bf16x8 af[4], bf[4];
#pragma unroll
      for (int mi = 0; mi < 4; ++mi) {
        int row = wr * 64 + mi * 16 + la;
        int off = row * 128 + (((q + 4 * kk) ^ (row & 7)) << 4);
        af[mi] = *(const bf16x8*)((const char*)smA + off);
      }
#pragma unroll
      for (int ni = 0; ni < 4; ++ni) {
        int row = wc * 64 + ni * 16 + la;
        int off = row * 128 + (((q + 4 * kk) ^ (row & 7)) << 4);
        bf[ni] = *(const bf16x8*)((const char*)smB + off);
      }
#pragma unroll
      for (int mi = 0; mi < 4; ++mi)
#pragma unroll
        for (int ni = 0; ni < 4; ++ni)
          acc[mi][ni] = __builtin_amdgcn_mfma_f32_16x16x32_bf16(af[mi], bf[ni], acc[mi][ni], 0, 0, 0);
    }
    __syncthreads();   // readers done before next overwrite
  }

  float* Pz = P + (size_t)blockIdx.z * M * N;
  const int r0 = q * 4;
#pragma unroll
  for (int mi = 0; mi < 4; ++mi) {
#pragma unroll
    for (int ni = 0; ni < 4; ++ni) {
      int n = n0 + wc * 64 + ni * 16 + la;
#pragma unroll
      for (int r = 0; r < 4; ++r) {
        int m = m0 + wr * 64 + mi * 16 + r0 + r;
        Pz[(size_t)m * N + n] = acc[mi][ni][r];
      }
    }
  }
}

// ---------------- gemm_part (64² named-reg version, for gemm2) ---------------
__global__ __launch_bounds__(256) void gemm_part(
    const unsigned short* __restrict__ A, const unsigned short* __restrict__ B,
    float* __restrict__ P, int M, int N, int K, int KS) {
  constexpr int BK = 64;
  __shared__ unsigned short smA[64 * BK];
  __shared__ unsigned short smB[64 * BK];
  const int t = threadIdx.x, wave = t >> 6, lane = t & 63;
  const int m0 = blockIdx.x * 64, n0 = blockIdx.y * 64;
  const int k0 = blockIdx.z * KS, k1 = k0 + KS;
  const int wr = wave >> 1, wc = wave & 1;

  f32x4 acc00 = (f32x4)0.f, acc01 = (f32x4)0.f;
  f32x4 acc10 = (f32x4)0.f, acc11 = (f32x4)0.f;

  const int off0 = t * 16, off1 = (256 + t) * 16;
  const int ar0 = off0 >> 7, ac0 = off0 & 127;
  const int ar1 = off1 >> 7, ac1 = off1 & 127;
  const int ad0 = off0 ^ ((ar0 & 7) << 4);
  const int ad1 = off1 ^ ((ar1 & 7) << 4);
  const char* Ab0 = (const char*)A + ((size_t)(m0 + ar0) * K) * 2 + ac0;
  const char* Ab1 = (const char*)A + ((size_t)(m0 + ar1) * K) * 2 + ac1;
  const char* Bb0 = (const char*)B + ((size_t)(n0 + ar0) * K) * 2 + ac0;
  const char* Bb1 = (const char*)B + ((size_t)(n0 + ar1) * K) * 2 + ac1;

  const int la = lane & 15;
  const int kb0 = (lane >> 4) * 16;
  const int rA0 = wr * 32 + la,      rA1 = wr * 32 + 16 + la;
  const int rB0 = wc * 32 + la,      rB1 = wc * 32 + 16 + la;
  const int oA0 = (rA0 * 128 + kb0) ^ ((rA0 & 7) << 4);
  const int oA1 = (rA1 * 128 + kb0) ^ ((rA1 & 7) << 4);
  const int oB0 = (rB0 * 128 + kb0) ^ ((rB0 & 7) << 4);
  const int oB1 = (rB1 * 128 + kb0) ^ ((rB1 & 7) << 4);

  uint4 ra0 = *(const uint4*)(Ab0 + (size_t)k0 * 2);
  uint4 ra1 = *(const uint4*)(Ab1 + (size_t)k0 * 2);
  uint4 rb0 = *(const uint4*)(Bb0 + (size_t)k0 * 2);
  uint4 rb1 = *(const uint4*)(Bb1 + (size_t)k0 * 2);

  for (int kt = k0; kt < k1; kt += BK) {
    __syncthreads();
    *(uint4*)((char*)smA + ad0) = ra0;
    *(uint4*)((char*)smA + ad1) = ra1;
    *(uint4*)((char*)smB + ad0) = rb0;
    *(uint4*)((char*)smB + ad1) = rb1;
    __syncthreads();
    const int ktn = kt + BK;
    if (ktn < k1) {
      ra0 = *(const uint4*)(Ab0 + (size_t)ktn * 2);
      ra1 = *(const uint4*)(Ab1 + (size_t)ktn * 2);
      rb0 = *(const uint4*)(Bb0 + (size_t)ktn * 2);
      rb1 = *(const uint4*)(Bb1 + (size_t)ktn * 2);
    }
#pragma unroll
    for (int kk = 0; kk < 2; ++kk) {
      const int kb = kk * 64;
      bf16x8 af0 = *(const bf16x8*)((const char*)smA + (oA0 ^ kb));
      bf16x8 af1 = *(const bf16x8*)((const char*)smA + (oA1 ^ kb));
      bf16x8 bf0 = *(const bf16x8*)((const char*)smB + (oB0 ^ kb));
      bf16x8 bf1 = *(const bf16x8*)((const char*)smB + (oB1 ^ kb));
      acc00 = __builtin_amdgcn_mfma_f32_16x16x32_bf16(af0, bf0, acc00, 0, 0, 0);
      acc01 = __builtin_amdgcn_mfma_f32_16x16x32_bf16(af0, bf1, acc01, 0, 0, 0);
      acc10 = __builtin_amdgcn_mfma_f32_16x16x32_bf16(af1, bf0, acc10, 0, 0, 0);
      acc11 = __builtin_amdgcn_mfma_f32_16x16x32_bf16(af1, bf1, acc11, 0, 0, 0);
    }
  }

  float* Pz = P + (size_t)blockIdx.z * M * N;
  const int r0 = (lane >> 4) * 4;
  const int cn = lane & 15;
  const int mA = m0 + wr * 32 + r0;
  const int nA = n0 + wc * 32 + cn;
#pragma unroll
  for (int r = 0; r < 4; ++r) {
    Pz[(size_t)(mA + r) * N + nA]           = acc00[r];
    Pz[(size_t)(mA + r) * N + nA + 16]      = acc01[r];
    Pz[(size_t)(mA + 16 + r) * N + nA]      = acc10[r];
    Pz[(size_t)(mA + 16 + r) * N + nA + 16] = acc11[r];
  }
}

// ------- reduce_h3: sum 4 K-split slabs + bias -> relu -> split-bf16 -> H3
__global__ __launch_bounds__(256) void reduce_h3_kernel(
    const float* __restrict__ P, const float* __restrict__ bias,
    unsigned short* __restrict__ Hb) {
  const int M = 4096, N = 512;
  int g = blockIdx.x * 256 + threadIdx.x;   // 524288 threads
  int m = g >> 7;
  int n4 = (g & 127) << 2;
  const float* p = P + (size_t)m * N + n4;
  const size_t slab = (size_t)M * N;
  float4 v0 = *(const float4*)p;
  float4 v1 = *(const float4*)(p + slab);
  float4 v2 = *(const float4*)(p + 2 * slab);
  float4 v3 = *(const float4*)(p + 3 * slab);
  float4 vb = *(const float4*)(bias + n4);
  float r[4] = {v0.x + v1.x + v2.x + v3.x + vb.x,
                v0.y + v1.y + v2.y + v3.y + vb.y,
                v0.z + v1.z + v2.z + v3.z + vb.z,
                v0.w + v1.w + v2.w + v3.w + vb.w};
  u16x4 h4, l4;
#pragma unroll
  for (int i = 0; i < 4; ++i) {
    float v = fmaxf(r[i], 0.0f);
    unsigned short h = f2bf(v);
    h4[i] = h;
    l4[i] = f2bf(v - bf2f(h));
  }
  size_t rbase = (size_t)m * 1536;
  *(u16x4*)(Hb + rbase + n4)        = h4;
  *(u16x4*)(Hb + rbase + 512 + n4)  = h4;
  *(u16x4*)(Hb + rbase + 1024 + n4) = l4;
}

// ------- reduce_com: sum 4 K-split slabs + bias -> f32 com
__global__ __launch_bounds__(256) void reduce_com_kernel(
    const float* __restrict__ P, const float* __restrict__ bias,
    float* __restrict__ com) {
  const int M = 4096, N = 128;
  int g = blockIdx.x * 256 + threadIdx.x;   // 131072 threads
  int m = g >> 5;
  int n4 = (g & 31) << 2;
  const float* p = P + (size_t)m * N + n4;
  const size_t slab = (size_t)M * N;
  float4 a0 = *(const float4*)p;
  float4 a1 = *(const float4*)(p + slab);
  float4 a2 = *(const float4*)(p + 2 * slab);
  float4 a3 = *(const float4*)(p + 3 * slab);
  float4 vb = *(const float4*)(bias + n4);
  float4 r;
  r.x = a0.x + a1.x + a2.x + a3.x + vb.x;
  r.y = a0.y + a1.y + a2.y + a3.y + vb.y;
  r.z = a0.z + a1.z + a2.z + a3.z + vb.z;
  r.w = a0.w + a1.w + a2.w + a3.w + vb.w;
  *(float4*)(com + (size_t)m * N + n4) = r;
}

// ---------------- prep_gates: 48 gate matrices -> (g0,g1,g2,g3) table ---------
__global__ __launch_bounds__(64) void prep_gates(const float* __restrict__ asz,
                                                 float* __restrict__ gcoef) {
  int t = threadIdx.x;
  if (t < 48) {
    float phi = asz[t * 3 + 0], th = asz[t * 3 + 1], om = asz[t * 3 + 2];
    float sth, cth, sa, ca, sb, cb;
    sincosf(0.5f * th, &sth, &cth);
    sincosf(0.5f * (phi + om), &sa, &ca);
    sincosf(0.5f * (phi - om), &sb, &cb);
    float4 g;
    g.x =  ca * cth;   // g0 : Re m00 (= Re m11)
    g.y = -sa * cth;   // g1 : Im m00 (= -Im m11)
    g.z = -cb * sth;   // g2 : Re m01 (= -Re m10)
    g.w = -sb * sth;   // g3 : Im m01 (= Im m10)
    ((float4*)gcoef)[t] = g;
  }
}

// ---------------- quantum kernel: one block per batch item -------------------
__global__ __launch_bounds__(256) void quantum_kernel(
    const float* __restrict__ x, const float* __restrict__ com,
    const float* __restrict__ gcoef, float* __restrict__ out, QArgs qa) {
  __shared__ f32x2 st[4096];      // 32768 B
  __shared__ float xrow[2048];    //  8192 B  (total 40960 -> 4 blocks/CU)
  const int t = threadIdx.x;
  const int b = blockIdx.x;
  const float4* __restrict__ gc4 = (const float4*)gcoef;

  // stage x row (img angles); zero state
  {
    const float4* xs = (const float4*)(x + (size_t)b * 2048);
    ((float4*)xrow)[t] = xs[t];
    ((float4*)xrow)[t + 256] = xs[t + 256];
  }
#pragma unroll
  for (int s = 0; s < 16; ++s) st[s * 256 + t] = (f32x2){0.f, 0.f};
  __syncthreads();

  // init: H^{1..7} + FRQI(com,7): 256 real amps
  {
    int jj = t & 127, b0 = t >> 7;
    int p = __brev((unsigned)jj) >> 25;  // 7-bit reverse
    float ang = 0.5f * com[(size_t)b * 128 + p];
    float s = __sinf(ang), c = __cosf(ang);
    float val = (b0 ? s : c) * 0.08838834764831845f;  // 2^-3.5
    int j = (b0 << 11) | (jj << 4);
    *(f32x2*)((char*)st + (swz(j) << 3)) = (f32x2){val, 0.f};
  }
  __syncthreads();

  // 12 fused passes (4 Rot gates each), CNOTs folded into masks/roles
#pragma unroll 1
  for (int p = 0; p < 12; ++p) {
    // byte-swizzled coset base: srB = swz(rep)<<3, built per t-bit
    int srB = 0;
#pragma unroll
    for (int i = 0; i < 8; ++i) srB ^= ((t >> i) & 1) ? (int)qa.anp[p][i] : 0;

    // gate coefficients (wave-uniform loads) + per-thread role signs
    const int gi = (p / 3) * 12 + (p % 3) * 4;
    float4 gk0 = gc4[gi + 0], gk1 = gc4[gi + 1], gk2 = gc4[gi + 2], gk3 = gc4[gi + 3];
    unsigned sg0 = (unsigned)__popc(t & (int)qa.gm8[p][0]) << 31;
    unsigned sg1 = (unsigned)__popc(t & (int)qa.gm8[p][1]) << 31;
    unsigned sg2 = (unsigned)__popc(t & (int)qa.gm8[p][2]) << 31;
    unsigned sg3 = (unsigned)__popc(t & (int)qa.gm8[p][3]) << 31;

    int aB[16];
    f32x2 v[16];
#pragma unroll
    for (int s = 0; s < 16; ++s) {
      aB[s] = srB ^ (int)qa.xcs[p][s];
      v[s] = *(const f32x2*)((const char*)st + aB[s]);
    }

#pragma unroll
    for (int k = 0; k < 4; ++k) {
      float4 g = (k == 0) ? gk0 : (k == 1) ? gk1 : (k == 2) ? gk2 : gk3;
      unsigned sg = (k == 0) ? sg0 : (k == 1) ? sg1 : (k == 2) ? sg2 : sg3;
      f32x2 G0 = (f32x2)(g.x);
      f32x2 S1 = (f32x2)(xsign(g.y, sg));
      f32x2 S2 = (f32x2)(xsign(g.z, sg));
      f32x2 G3 = (f32x2)(g.w);
      const int bk = 1 << k;
#pragma unroll
      for (int s = 0; s < 16; ++s) {
        if (s & bk) continue;
        bfly(v[s], v[s | bk], G0, S1, S2, G3);
      }
    }
#pragma unroll
    for (int s = 0; s < 16; ++s) *(f32x2*)((char*)st + aB[s]) = v[s];
    __syncthreads();
  }

  // fused final FRQI(img,11) + readout:
  // per pair: |o1|^2-|o0|^2 = -(-1)^rho cos(x) (|a|^2-|b|^2) - 2 sin(x) <a,b>
  float accv = 0.f;
  {
    unsigned C0 = 0;
#pragma unroll
    for (int i = 0; i < 8; ++i) C0 ^= ((t >> i) & 1) ? qa.cmb_t[i] : 0u;
#pragma unroll
    for (int q = 0; q < 8; ++q) {
      unsigned C = C0 ^ qa.cmb_q[q];
      int aA = (int)(C & 0x7FF8u);
      int aB2 = aA ^ (int)qa.smF8;
      float ang = xrow[C >> 16];
      float sx = __sinf(ang), cx = __cosf(ang);
      f32x2 a = *(const f32x2*)((const char*)st + aA);
      f32x2 bb = *(const f32x2*)((const char*)st + aB2);
      float da = a.x * a.x + a.y * a.y;
      float db = bb.x * bb.x + bb.y * bb.y;
      float d = da - db;
      float dot = a.x * bb.x + a.y * bb.y;
      unsigned sgn = (C & 0x8000u) << 16;
      float dp = xsign(d, sgn);
      accv -= cx * dp + 2.0f * sx * dot;
    }
  }
  __syncthreads();   // all reads of st/xrow done before scratch reuse

  // reduce: wave shfl + cross-wave via xrow scratch
#pragma unroll
  for (int o = 32; o > 0; o >>= 1) accv += __shfl_down(accv, o, 64);
  if ((t & 63) == 0) xrow[t >> 6] = accv;
  __syncthreads();
  if (t == 0) out[b] = xrow[0] + xrow[1] + xrow[2] + xrow[3];
}

// ---------------------------------------------------------------------------
static inline int par16(int v) { return __builtin_popcount((unsigned)v) & 1; }

extern "C" void kernel_launch(void* const* d_in, const int* in_sizes, int n_in,
                              void* d_out, int out_size, void* d_ws, size_t ws_size,
                              hipStream_t stream) {
  (void)in_sizes; (void)n_in; (void)out_size; (void)ws_size;
  const float* x   = (const float*)d_in[0];
  const float* W1  = (const float*)d_in[1];
  const float* b1  = (const float*)d_in[2];
  const float* W2  = (const float*)d_in[3];
  const float* b2  = (const float*)d_in[4];
  const float* asz = (const float*)d_in[5];
  float* out = (float*)d_out;

  char* ws = (char*)d_ws;
  unsigned short* A3  = (unsigned short*)ws; ws += (size_t)4096 * 6144 * 2;
  unsigned short* B3T = (unsigned short*)ws; ws += (size_t)512 * 6144 * 2;
  unsigned short* H3  = (unsigned short*)ws; ws += (size_t)4096 * 1536 * 2;
  unsigned short* W23 = (unsigned short*)ws; ws += (size_t)128 * 1536 * 2;
  float* com = (float*)ws;                   ws += (size_t)4096 * 128 * 4;
  float* gcoef = (float*)ws;                 ws += (size_t)1024;
  float* P = (float*)ws;                     ws += (size_t)4 * 4096 * 512 * 4;  // 33.6 MB (gemm2 aliases: 4x4096x128 = 8.4 MB)

  // ----- host: lazy CNOT tracking (circuit is input-independent) -----
  QArgs qa;
  int cols[12], rows[12];
  for (int w = 0; w < 12; ++w) cols[w] = rows[w] = 1 << (11 - w);
  int hswz;
  for (int l = 0; l < 4; ++l) {
    for (int g = 0; g < 3; ++g) {
      int p = l * 3 + g;
      int m[4], grow[4];
      for (int k = 0; k < 4; ++k) {
        int w = g * 4 + k;
        m[k] = cols[w];
        grow[k] = rows[w];
      }
      for (int s = 0; s < 16; ++s) {
        int v = 0;
        for (int k = 0; k < 4; ++k)
          if (s & (1 << k)) v ^= m[k];
        hswz = v ^ (v >> 5) ^ (v >> 10);
        qa.xcs[p][s] = (uint16_t)(hswz << 3);
      }
      int mm[4] = {m[0], m[1], m[2], m[3]};
      int piv = 0;
      for (int k = 0; k < 4; ++k) {
        int pb = 31 - __builtin_clz((unsigned)mm[k]);
        piv |= 1 << pb;
        for (int k2 = k + 1; k2 < 4; ++k2)
          if (mm[k2] & (1 << pb)) mm[k2] ^= mm[k];
      }
      int npb[8], c = 0;
      for (int bit = 0; bit < 12; ++bit)
        if (!(piv & (1 << bit))) npb[c++] = bit;
      for (int i = 0; i < 8; ++i) {
        int bv = 1 << npb[i];
        hswz = bv ^ (bv >> 5) ^ (bv >> 10);
        qa.anp[p][i] = (uint16_t)(hswz << 3);
      }
      for (int k = 0; k < 4; ++k) {
        int mask8 = 0;
        for (int i = 0; i < 8; ++i)
          mask8 |= ((grow[k] >> npb[i]) & 1) << i;
        qa.gm8[p][k] = (uint8_t)mask8;
      }
    }
    int r = l % 11 + 1;
    for (int w = 0; w < 12; ++w) {
      int cw = w, tw = (w + r) % 12;
      cols[cw] ^= cols[tw];   // A <- A o L (CNOT ctrl=w, tgt=(w+r)%12)
      rows[tw] ^= rows[cw];   // A^-1 <- L o A^-1
    }
  }
  // final FRQI fold: combined constants, all GF2-linear in u = (q<<8)|t
  {
    int mF = cols[0];
    int hb = 31 - __builtin_clz((unsigned)mF);
    int lowmask = (1 << hb) - 1;
    auto jAof = [&](int u) { return ((u & ~lowmask) << 1) | (u & lowmask); };
    auto cmbof = [&](int j) -> uint32_t {
      int pidx = 0;
      for (int w = 1; w < 12; ++w)
        pidx |= par16(j & rows[w]) << (w - 1);
      int rho = par16(j & rows[0]);
      int sj = j ^ (j >> 5) ^ (j >> 10);
      return ((uint32_t)pidx << 16) | ((uint32_t)rho << 15) | (uint32_t)(sj << 3);
    };
    for (int i = 0; i < 8; ++i) qa.cmb_t[i] = cmbof(jAof(1 << i));
    for (int q = 0; q < 8; ++q) qa.cmb_q[q] = cmbof(jAof(q << 8));
    int sF = mF ^ (mF >> 5) ^ (mF >> 10);
    qa.smF8 = (uint32_t)(sF << 3);
  }

  // ----- pipeline -----
  conv_x_kernel<<<4096, 256, 0, stream>>>(x, A3);
  conv_w_kernel<<<dim3(32, 8), 256, 0, stream>>>(W1, B3T, 2048, 512);
  conv_w_kernel<<<dim3(8, 2), 256, 0, stream>>>(W2, W23, 512, 128);
  prep_gates<<<1, 64, 0, stream>>>(asz, gcoef);
  gemm128<<<dim3(32, 4, 4), 256, 0, stream>>>(A3, B3T, P, 4096, 512, 6144, 1536);
  reduce_h3_kernel<<<2048, 256, 0, stream>>>(P, b1, H3);
  gemm_part<<<dim3(64, 2, 4), 256, 0, stream>>>(H3, W23, P, 4096, 128, 1536, 384);
  reduce_com_kernel<<<512, 256, 0, stream>>>(P, b2, com);
  quantum_kernel<<<4096, 256, 0, stream>>>(x, com, gcoef, out, qa);
}